// Round 14
// baseline (2664.681 us; speedup 1.0000x reference)
//
#include <hip/hip_runtime.h>

#define N_NODES 131072
#define E_EDGES 262144
#define L_SEG 16384
#define G_SEG 2048
#define D_FEAT 300
#define NUM_LAYERS 5
#define MCHUNK 32768        // GEMM row chunk (N_NODES % MCHUNK == 0; % 256 == 0)
#define RB (MCHUNK / 256)   // row-blocks per GEMM dispatch = 128 (div by 8)
#define HS 320              // h row stride in u16 (300 data + 20 pad; 640B = 5 lines)
#define KP1 320             // padded K for gemm1 (agg width; 640B rows)
#define KP2 640             // padded K for gemm2 (tbuf width; 1280B rows)
#define NP1 640             // W1T rows (600 -> 640)
#define NP2 384             // W2T rows (300 -> 384)

typedef unsigned short u16;
typedef unsigned int u32;
typedef __attribute__((ext_vector_type(8))) short short8v;   // 8 bf16 = 4 VGPR
typedef __attribute__((ext_vector_type(4))) float f32x4;

struct __align__(16) U128 { u32 a, b, c, d; };
struct __align__(8) U64 { u32 a, b; };

// ---- bf16 <-> f32 helpers (RNE) ----
__device__ __forceinline__ float bf2f(u16 u) { return __uint_as_float(((u32)u) << 16); }
__device__ __forceinline__ u16 f2bf(float f) {
  u32 x = __float_as_uint(f);
  x += 0x7fffu + ((x >> 16) & 1u);
  return (u16)(x >> 16);
}
__device__ __forceinline__ u32 pack2(float x, float y) {
  return (u32)f2bf(x) | ((u32)f2bf(y) << 16);
}

// ---- async global->LDS: per-lane 16B from gptr, LDS dest = uniform base + lane*16 ----
__device__ __forceinline__ void gl2lds16(const void* g, void* l) {
  auto gp = reinterpret_cast<const __attribute__((address_space(1))) void*>(
      reinterpret_cast<uintptr_t>(g));
  auto lp = reinterpret_cast<__attribute__((address_space(3))) void*>(
      reinterpret_cast<uintptr_t>(l));
  __builtin_amdgcn_global_load_lds(gp, lp, 16, 0, 0);
}

// ---------------- h = x_emb1[x[:,0]] + x_emb2[x[:,1]]  (bf16, stride HS) ----------------
__global__ void k_init_h(const int* __restrict__ x, const float* __restrict__ e1,
                         const float* __restrict__ e2, u16* __restrict__ h) {
  int i = blockIdx.x * blockDim.x + threadIdx.x;  // N*80 ushort4 groups
  if (i >= N_NODES * 80) return;
  int n = i / 80, q = i - n * 80;
  int col = q * 4;
  ushort4 o = make_ushort4(0, 0, 0, 0);
  if (col < 300) {
    int x0 = x[2 * n], x1 = x[2 * n + 1];
    float4 va = *(const float4*)(e1 + (size_t)x0 * D_FEAT + col);
    float4 vb = *(const float4*)(e2 + (size_t)x1 * D_FEAT + col);
    o.x = f2bf(va.x + vb.x); o.y = f2bf(va.y + vb.y);
    o.z = f2bf(va.z + vb.z); o.w = f2bf(va.w + vb.w);
  }
  *(ushort4*)(h + (size_t)n * HS + col) = o;
}

// ---------------- weight prep: WT[n][k] = w[k][n], bf16, zero-padded ----------------
__global__ void k_prepw(const float* __restrict__ w, u16* __restrict__ wt,
                        int K, int Ncol, int NP, int KP) {
  int l = blockIdx.y;
  int i = blockIdx.x * blockDim.x + threadIdx.x;
  if (i >= NP * KP) return;
  int n = i / KP, k = i - n * KP;
  float v = (n < Ncol && k < K) ? w[(size_t)l * K * Ncol + (size_t)k * Ncol + n] : 0.f;
  wt[(size_t)l * NP * KP + i] = f2bf(v);
}

// ---------------- CSR build ----------------
__global__ void k_zero(float* __restrict__ p, int n) {
  int i = blockIdx.x * blockDim.x + threadIdx.x;
  if (i < n) p[i] = 0.f;
}
__global__ void k_hist(const int* __restrict__ ei, int* __restrict__ cnt) {
  int e = blockIdx.x * blockDim.x + threadIdx.x;
  if (e < E_EDGES) atomicAdd(&cnt[ei[E_EDGES + e]], 1);
}
__global__ __launch_bounds__(1024) void k_scan(const int* __restrict__ cnt,
                                               int* __restrict__ offs,
                                               int* __restrict__ cursor) {
  __shared__ int part[1024];
  int t = threadIdx.x;
  int base = t * 128;
  int s = 0;
  for (int i = 0; i < 128; i++) s += cnt[base + i];
  part[t] = s;
  __syncthreads();
  for (int off = 1; off < 1024; off <<= 1) {
    int v = (t >= off) ? part[t - off] : 0;
    __syncthreads();
    part[t] += v;
    __syncthreads();
  }
  int run = (t == 0) ? 0 : part[t - 1];
  for (int i = 0; i < 128; i++) {
    offs[base + i] = run;
    cursor[base + i] = run;
    run += cnt[base + i];
  }
  if (t == 1023) offs[N_NODES] = run;
}
__global__ void k_fill(const int* __restrict__ ei, int* __restrict__ cursor,
                       int* __restrict__ elist) {
  int e = blockIdx.x * blockDim.x + threadIdx.x;
  if (e < E_EDGES) {
    int p = atomicAdd(&cursor[ei[E_EDGES + e]], 1);
    elist[p] = e;
  }
}

// ---------------- gather-aggregate (h already normalized) ----------------
// One wave per node; edge loop unrolled 2-wide (both edges' h-rows in flight).
__global__ void k_gather(const u32* __restrict__ h, const int* __restrict__ ei,
                         const int* __restrict__ ea, const int* __restrict__ offs,
                         const int* __restrict__ elist, const float* __restrict__ sc1,
                         const float* __restrict__ sc2, const float* __restrict__ ee1,
                         const float* __restrict__ ee2, u32* __restrict__ agg) {
  int n = (blockIdx.x << 2) + (threadIdx.x >> 6);
  int lane = threadIdx.x & 63;
  int j0 = lane, j1 = lane + 64, j2 = lane + 128;  // u32 indices (data < 150)
  float ax0, ay0, ax1, ay1, ax2 = 0.f, ay2 = 0.f;
  const u32* hn = h + (size_t)n * (HS / 2);
  {
    u32 u = hn[j0];
    ax0 = bf2f((u16)(u & 0xffffu)) + sc1[2 * j0] + sc2[2 * j0];
    ay0 = bf2f((u16)(u >> 16)) + sc1[2 * j0 + 1] + sc2[2 * j0 + 1];
    u = hn[j1];
    ax1 = bf2f((u16)(u & 0xffffu)) + sc1[2 * j1] + sc2[2 * j1];
    ay1 = bf2f((u16)(u >> 16)) + sc1[2 * j1 + 1] + sc2[2 * j1 + 1];
    if (j2 < 150) {
      u = hn[j2];
      ax2 = bf2f((u16)(u & 0xffffu)) + sc1[2 * j2] + sc2[2 * j2];
      ay2 = bf2f((u16)(u >> 16)) + sc1[2 * j2 + 1] + sc2[2 * j2 + 1];
    }
  }
  int p = offs[n], pe = offs[n + 1];
  while (p + 2 <= pe) {
    int eA = elist[p], eB = elist[p + 1];
    int sA = ei[eA], sB = ei[eB];
    int a0A = ea[2 * eA], a1A = ea[2 * eA + 1];
    int a0B = ea[2 * eB], a1B = ea[2 * eB + 1];
    const u32* hA = h + (size_t)sA * (HS / 2);
    const u32* hB = h + (size_t)sB * (HS / 2);
    const float* p1A = ee1 + (size_t)a0A * D_FEAT;
    const float* p2A = ee2 + (size_t)a1A * D_FEAT;
    const float* p1B = ee1 + (size_t)a0B * D_FEAT;
    const float* p2B = ee2 + (size_t)a1B * D_FEAT;
    u32 uA0 = hA[j0], uA1 = hA[j1];
    u32 uB0 = hB[j0], uB1 = hB[j1];
    u32 uA2 = 0, uB2 = 0;
    if (j2 < 150) { uA2 = hA[j2]; uB2 = hB[j2]; }
    ax0 += bf2f((u16)(uA0 & 0xffffu)) + p1A[2 * j0] + p2A[2 * j0];
    ay0 += bf2f((u16)(uA0 >> 16)) + p1A[2 * j0 + 1] + p2A[2 * j0 + 1];
    ax1 += bf2f((u16)(uA1 & 0xffffu)) + p1A[2 * j1] + p2A[2 * j1];
    ay1 += bf2f((u16)(uA1 >> 16)) + p1A[2 * j1 + 1] + p2A[2 * j1 + 1];
    if (j2 < 150) {
      ax2 += bf2f((u16)(uA2 & 0xffffu)) + p1A[2 * j2] + p2A[2 * j2];
      ay2 += bf2f((u16)(uA2 >> 16)) + p1A[2 * j2 + 1] + p2A[2 * j2 + 1];
    }
    ax0 += bf2f((u16)(uB0 & 0xffffu)) + p1B[2 * j0] + p2B[2 * j0];
    ay0 += bf2f((u16)(uB0 >> 16)) + p1B[2 * j0 + 1] + p2B[2 * j0 + 1];
    ax1 += bf2f((u16)(uB1 & 0xffffu)) + p1B[2 * j1] + p2B[2 * j1];
    ay1 += bf2f((u16)(uB1 >> 16)) + p1B[2 * j1 + 1] + p2B[2 * j1 + 1];
    if (j2 < 150) {
      ax2 += bf2f((u16)(uB2 & 0xffffu)) + p1B[2 * j2] + p2B[2 * j2];
      ay2 += bf2f((u16)(uB2 >> 16)) + p1B[2 * j2 + 1] + p2B[2 * j2 + 1];
    }
    p += 2;
  }
  if (p < pe) {  // tail edge
    int e = elist[p];
    int s = ei[e];
    int a0 = ea[2 * e], a1 = ea[2 * e + 1];
    const u32* hs = h + (size_t)s * (HS / 2);
    const float* p1 = ee1 + (size_t)a0 * D_FEAT;
    const float* p2 = ee2 + (size_t)a1 * D_FEAT;
    u32 u = hs[j0];
    ax0 += bf2f((u16)(u & 0xffffu)) + p1[2 * j0] + p2[2 * j0];
    ay0 += bf2f((u16)(u >> 16)) + p1[2 * j0 + 1] + p2[2 * j0 + 1];
    u = hs[j1];
    ax1 += bf2f((u16)(u & 0xffffu)) + p1[2 * j1] + p2[2 * j1];
    ay1 += bf2f((u16)(u >> 16)) + p1[2 * j1 + 1] + p2[2 * j1 + 1];
    if (j2 < 150) {
      u = hs[j2];
      ax2 += bf2f((u16)(u & 0xffffu)) + p1[2 * j2] + p2[2 * j2];
      ay2 += bf2f((u16)(u >> 16)) + p1[2 * j2 + 1] + p2[2 * j2 + 1];
    }
  }
  u32* ao = agg + (size_t)n * (KP1 / 2);
  ao[j0] = pack2(ax0, ay0);
  ao[j1] = pack2(ax1, ay1);
  if (j2 < 150) ao[j2] = pack2(ax2, ay2);
  else if (j2 < 160) ao[j2] = 0u;
}

// ---------------- MFMA GEMM: C = A@W^T + bias, opt relu, opt fused col-stats ----------------
// 256x128 tile, 8 waves (512 thr), BK=32, double-buffered fragment-ordered LDS
// (R13-proven). 1D grid with XCD-chunked swizzle: bid -> xcd=bid&7, j=bid>>3,
// row = xcd*(RB/8) + j/ncb, col = j%ncb  (bijective; same-A-panel col-tiles run
// back-to-back on one XCD -> A-panel L2 reuse). All C strides are 128B-aligned
// (no partial-line write-allocate RMW). Epilogue: 4 passes of 64 rows via LDS
// [64][132], 8B coalesced stores, optional fused per-column sum/sumsq
// (stats[0..303] sum, stats[304..607] sumsq).
template <bool RELU, int KP>
__global__ __launch_bounds__(512) void k_gemm_mfma(const u16* __restrict__ A,
                                                   const u16* __restrict__ WT,
                                                   const float* __restrict__ bias,
                                                   u16* __restrict__ C, int Ncol,
                                                   int Cstride, int ncb,
                                                   float* __restrict__ stats) {
  __shared__ __align__(16) u16 SL[24576];  // 48KB: buf0 = SL[0..12287], buf1 = SL[12288..]
  int t = threadIdx.x;
  int w = t >> 6, lane = t & 63;
  int bid = blockIdx.x;
  int xcd = bid & 7, j = bid >> 3;
  int rowb = xcd * (RB / 8) + j / ncb;
  int colb = j - (j / ncb) * ncb;
  int brow = rowb << 8, bcol = colb << 7;
  int wr = w >> 1, wc = w & 1;
  int r16 = lane & 15, kq = lane >> 4;
  int rq = kq << 2;

  f32x4 zero4 = {0.f, 0.f, 0.f, 0.f};
  f32x4 acc[4][4];
#pragma unroll
  for (int mi = 0; mi < 4; mi++)
#pragma unroll
    for (int nj = 0; nj < 4; nj++) acc[mi][nj] = zero4;

  int m0 = 2 * w, m1 = m0 + 1;
  const u16* gA0 = A + (size_t)(brow + m0 * 16 + r16) * KP + kq * 8;
  const u16* gA1 = A + (size_t)(brow + m1 * 16 + r16) * KP + kq * 8;
  const u16* gB = WT + (size_t)(bcol + w * 16 + r16) * KP + kq * 8;

  // prologue: stage tile k0=0 into buffer 0
  gl2lds16(gA0, SL + m0 * 512);
  gl2lds16(gA1, SL + m1 * 512);
  gl2lds16(gB, SL + 8192 + w * 512);
  __syncthreads();

  int cur = 0;
  for (int k0 = 0; k0 < KP; k0 += 32) {
    u16* curb = SL + cur * 12288;
    u16* nxtb = SL + (cur ^ 1) * 12288;
    if (k0 + 32 < KP) {  // issue next tile; latency hides under this tile's compute
      gl2lds16(gA0 + k0 + 32, nxtb + m0 * 512);
      gl2lds16(gA1 + k0 + 32, nxtb + m1 * 512);
      gl2lds16(gB + k0 + 32, nxtb + 8192 + w * 512);
    }
    short8v af[4], bf[4];
#pragma unroll
    for (int mi = 0; mi < 4; mi++)
      af[mi] = *(const short8v*)(curb + (wr * 4 + mi) * 512 + lane * 8);
#pragma unroll
    for (int nj = 0; nj < 4; nj++)
      bf[nj] = *(const short8v*)(curb + 8192 + (wc * 4 + nj) * 512 + lane * 8);
#pragma unroll
    for (int mi = 0; mi < 4; mi++)
#pragma unroll
      for (int nj = 0; nj < 4; nj++)
        acc[mi][nj] = __builtin_amdgcn_mfma_f32_16x16x32_bf16(af[mi], bf[nj], acc[mi][nj], 0, 0, 0);
    __syncthreads();  // next-tile loads complete; all reads of curb done
    cur ^= 1;
  }

  // ---- epilogue: 4 passes of 64 rows via LDS [64][132] u16, 8B coalesced stores ----
#pragma unroll
  for (int p = 0; p < 4; p++) {
    if (wr == p) {
#pragma unroll
      for (int nj = 0; nj < 4; nj++) {
        int col = wc * 64 + nj * 16 + r16;
        int gcol = bcol + col;
        bool live = gcol < Ncol;
        float bs = live ? bias[gcol] : 0.f;
#pragma unroll
        for (int mi = 0; mi < 4; mi++) {
#pragma unroll
          for (int jj = 0; jj < 4; jj++) {
            float v = acc[mi][nj][jj] + bs;   // D row = (lane>>4)*4+jj, col = lane&15
            if (RELU) v = fmaxf(v, 0.f);
            if (!live) v = 0.f;
            SL[(mi * 16 + rq + jj) * 132 + col] = f2bf(v);
          }
        }
      }
    }
    __syncthreads();
    {
      int r = t >> 3, s = t & 7;  // row 0..63, col-oct 0..7
      size_t grow = (size_t)(brow + p * 64 + r) * Cstride;
#pragma unroll
      for (int c = 0; c < 2; c++) {
        int colu = s * 16 + c * 8;
        int gcol = bcol + colu;
        if (gcol + 8 <= Cstride) {
          U64 v0 = *(const U64*)(SL + r * 132 + colu);
          U64 v1 = *(const U64*)(SL + r * 132 + colu + 4);
          *(U64*)(C + grow + gcol) = v0;
          *(U64*)(C + grow + gcol + 4) = v1;
        }
      }
    }
    // fused column stats over this pass's 64 rows (bf16 bits == what h stores)
    if (stats != nullptr && t < 128) {
      int gcol = bcol + t;
      if (gcol < Ncol) {
        float s0 = 0.f, q0 = 0.f;
#pragma unroll 8
        for (int r = 0; r < 64; r++) {
          float v = bf2f(SL[r * 132 + t]);
          s0 += v;
          q0 = fmaf(v, v, q0);
        }
        atomicAdd(stats + gcol, s0);
        atomicAdd(stats + 304 + gcol, q0);
      }
    }
    __syncthreads();
  }
}

// ---------------- BN finalize: a = rsqrt(var+eps)*gamma, c = beta - mu*a (pads -> 0) ----------------
__global__ void k_bnfin(const float* __restrict__ sums, const float* __restrict__ gamma,
                        const float* __restrict__ beta, float* __restrict__ fa,
                        float* __restrict__ fc) {
  int d = blockIdx.x * blockDim.x + threadIdx.x;
  if (d >= HS) return;
  float a = 0.f, c = 0.f;
  if (d < D_FEAT) {
    const float inv = 1.f / (float)N_NODES;
    float mu = sums[d] * inv;
    float var = sums[304 + d] * inv - mu * mu;
    a = rsqrtf(var + 1e-5f) * gamma[d];
    c = beta[d] - mu * a;
  }
  fa[d] = a;
  fc[d] = c;
}

// ---------------- BN normalize (+opt relu), 8-wide, in place on bf16 (stride HS) ----------------
__global__ void k_bnnorm(u16* __restrict__ h, const float* __restrict__ fa,
                         const float* __restrict__ fc, int relu) {
  int i = blockIdx.x * blockDim.x + threadIdx.x;  // N*40 groups of 8
  if (i >= N_NODES * 40) return;
  int n = i / 40, q = i - n * 40;
  int col = q * 8;
  u16* hp = h + (size_t)n * HS + col;
  float4 a0 = *(const float4*)(fa + col);
  float4 a1 = *(const float4*)(fa + col + 4);
  float4 c0 = *(const float4*)(fc + col);
  float4 c1 = *(const float4*)(fc + col + 4);
  ushort4 u0 = *(ushort4*)hp;
  ushort4 u1 = *(ushort4*)(hp + 4);
  float r0, r1, r2, r3, r4, r5, r6, r7;
#define BN1(res, uv, A, C)                       \
  res = fmaf((A), bf2f(uv), (C));                \
  if (relu) res = fmaxf(res, 0.f);
  BN1(r0, u0.x, a0.x, c0.x) BN1(r1, u0.y, a0.y, c0.y)
  BN1(r2, u0.z, a0.z, c0.z) BN1(r3, u0.w, a0.w, c0.w)
  BN1(r4, u1.x, a1.x, c1.x) BN1(r5, u1.y, a1.y, c1.y)
  BN1(r6, u1.z, a1.z, c1.z) BN1(r7, u1.w, a1.w, c1.w)
#undef BN1
  ushort4 o0, o1;
  o0.x = f2bf(r0); o0.y = f2bf(r1); o0.z = f2bf(r2); o0.w = f2bf(r3);
  o1.x = f2bf(r4); o1.y = f2bf(r5); o1.z = f2bf(r6); o1.w = f2bf(r7);
  *(ushort4*)hp = o0;
  *(ushort4*)(hp + 4) = o1;
}

// ---------------- segment means (sorted ids, binary search) ----------------
__device__ __forceinline__ int lowerBound(const int* __restrict__ a, int n, int v) {
  int lo = 0, hi = n;
  while (lo < hi) {
    int m = (lo + hi) >> 1;
    if (a[m] < v) lo = m + 1; else hi = m;
  }
  return lo;
}

__global__ void k_lower(const u16* __restrict__ h, const int* __restrict__ lb,
                        float* __restrict__ lower) {
  int g = blockIdx.x;
  int s = lowerBound(lb, N_NODES, g);
  int e = lowerBound(lb, N_NODES, g + 1);
  float invc = 1.f / (float)max(e - s, 1);
  for (int d = threadIdx.x; d < D_FEAT; d += 256) {
    float acc = 0.f;
    for (int r = s; r < e; r++) acc += bf2f(h[(size_t)r * HS + d]);
    lower[(size_t)g * D_FEAT + d] = acc * invc;
  }
}

__global__ void k_pooled(const float* __restrict__ lower, const int* __restrict__ ub,
                         float* __restrict__ pooled) {
  int g = blockIdx.x, br = blockIdx.y;
  int s = lowerBound(ub, L_SEG, g);
  int e = lowerBound(ub, L_SEG, g + 1);
  float invc = 1.f / (float)max(e - s, 1);
  for (int d = threadIdx.x; d < D_FEAT; d += 256) {
    float acc = 0.f;
    for (int i = s; i < e; i++) {
      int row = br ? (i - 1 + L_SEG) % L_SEG : i;
      acc += lower[(size_t)row * D_FEAT + d];
    }
    pooled[((size_t)br * G_SEG + g) * D_FEAT + d] = acc * invc;
  }
}

__global__ __launch_bounds__(256) void k_classify(const float* __restrict__ pooled,
                                                  const float* __restrict__ w1,
                                                  const float* __restrict__ b1,
                                                  const float* __restrict__ w2,
                                                  const float* __restrict__ b2,
                                                  float* __restrict__ out) {
  __shared__ float p[D_FEAT];
  __shared__ float red[4];
  int g = blockIdx.x, br = blockIdx.y;
  const float* pr = pooled + ((size_t)br * G_SEG + g) * D_FEAT;
  for (int d = threadIdx.x; d < D_FEAT; d += 256) p[d] = pr[d];
  __syncthreads();
  float partial = 0.f;
  for (int j = threadIdx.x; j < D_FEAT; j += 256) {
    float acc = b1[j];
    for (int k = 0; k < D_FEAT; k++) acc = fmaf(p[k], w1[(size_t)k * D_FEAT + j], acc);
    acc = fmaxf(acc, 0.f);
    partial += acc * w2[j];
  }
  for (int off = 32; off; off >>= 1) partial += __shfl_down(partial, off, 64);
  int lane = threadIdx.x & 63, wid = threadIdx.x >> 6;
  if (lane == 0) red[wid] = partial;
  __syncthreads();
  if (threadIdx.x == 0) out[(size_t)br * G_SEG + g] = red[0] + red[1] + red[2] + red[3] + b2[0];
}

extern "C" void kernel_launch(void* const* d_in, const int* in_sizes, int n_in,
                              void* d_out, int out_size, void* d_ws, size_t ws_size,
                              hipStream_t stream) {
  const int* x = (const int*)d_in[0];
  const int* ei = (const int*)d_in[1];
  const int* ea = (const int*)d_in[2];
  const int* lb = (const int*)d_in[3];
  const int* ub = (const int*)d_in[4];
  const float* xe1 = (const float*)d_in[5];
  const float* xe2 = (const float*)d_in[6];
  const float* ee1 = (const float*)d_in[7];
  const float* ee2 = (const float*)d_in[8];
  const float* w1 = (const float*)d_in[9];
  const float* b1 = (const float*)d_in[10];
  const float* w2 = (const float*)d_in[11];
  const float* b2 = (const float*)d_in[12];
  const float* gam = (const float*)d_in[13];
  const float* bet = (const float*)d_in[14];
  const float* cw1 = (const float*)d_in[15];
  const float* cb1 = (const float*)d_in[16];
  const float* cw2 = (const float*)d_in[17];
  const float* cb2 = (const float*)d_in[18];
  float* out = (float*)d_out;

  // ---- workspace (~217 MB; known-safe >= 255.59 MB from R3 tier-B) ----
  char* base = (char*)d_ws;
  size_t off = 0;
  auto alloc = [&](size_t bytes) -> void* {
    void* p = base + off;
    off += (bytes + 255) & ~(size_t)255;
    return p;
  };
  u16* h = (u16*)alloc((size_t)N_NODES * HS * 2);            // 83.9 MB
  u16* agg = (u16*)alloc((size_t)N_NODES * KP1 * 2);         // 83.9 MB
  u16* tbuf = (u16*)alloc((size_t)MCHUNK * KP2 * 2);         // 41.9 MB
  u16* W1T = (u16*)alloc((size_t)NUM_LAYERS * NP1 * KP1 * 2);
  u16* W2T = (u16*)alloc((size_t)NUM_LAYERS * NP2 * KP2 * 2);
  int* cnt = (int*)alloc((size_t)N_NODES * 4);
  int* offs = (int*)alloc((size_t)(N_NODES + 1) * 4);
  int* cursor = (int*)alloc((size_t)N_NODES * 4);
  int* elist = (int*)alloc((size_t)E_EDGES * 4);
  float* stats = (float*)alloc(608 * 4);   // sum[0..303], sumsq[304..607]
  float* aff_a = (float*)alloc(HS * 4);
  float* aff_c = (float*)alloc(HS * 4);
  float* lower = (float*)tbuf;                               // alias (post-loop only)
  float* pooled = lower + (size_t)L_SEG * D_FEAT;

  if (ws_size < off) {
    k_zero<<<(out_size + 255) / 256, 256, 0, stream>>>(out, out_size);
    return;
  }

  const int NT = 256;

  k_prepw<<<dim3((NP1 * KP1 + NT - 1) / NT, NUM_LAYERS), NT, 0, stream>>>(w1, W1T, 300, 600, NP1, KP1);
  k_prepw<<<dim3((NP2 * KP2 + NT - 1) / NT, NUM_LAYERS), NT, 0, stream>>>(w2, W2T, 600, 300, NP2, KP2);

  k_zero<<<(N_NODES + NT - 1) / NT, NT, 0, stream>>>((float*)cnt, N_NODES);
  k_hist<<<(E_EDGES + NT - 1) / NT, NT, 0, stream>>>(ei, cnt);
  k_scan<<<1, 1024, 0, stream>>>(cnt, offs, cursor);
  k_fill<<<(E_EDGES + NT - 1) / NT, NT, 0, stream>>>(ei, cursor, elist);

  k_init_h<<<(N_NODES * 80 + NT - 1) / NT, NT, 0, stream>>>(x, xe1, xe2, h);

  for (int l = 0; l < NUM_LAYERS; l++) {
    k_gather<<<N_NODES / 4, NT, 0, stream>>>(
        (const u32*)h, ei, ea, offs, elist,
        ee1 + ((size_t)l * 6 + 4) * D_FEAT, ee2 + (size_t)l * 3 * D_FEAT,
        ee1 + (size_t)l * 6 * D_FEAT, ee2 + (size_t)l * 3 * D_FEAT, (u32*)agg);
    k_zero<<<3, NT, 0, stream>>>(stats, 608);
    for (int c0 = 0; c0 < N_NODES; c0 += MCHUNK) {
      k_gemm_mfma<true, KP1><<<5 * RB, 512, 0, stream>>>(
          agg + (size_t)c0 * KP1, W1T + (size_t)l * NP1 * KP1, b1 + (size_t)l * 600,
          tbuf, 600, KP2, 5, nullptr);
      k_gemm_mfma<false, KP2><<<3 * RB, 512, 0, stream>>>(
          tbuf, W2T + (size_t)l * NP2 * KP2, b2 + (size_t)l * 300,
          h + (size_t)c0 * HS, 300, HS, 3, stats);
    }
    k_bnfin<<<2, NT, 0, stream>>>(stats, gam + (size_t)l * 300, bet + (size_t)l * 300,
                                  aff_a, aff_c);
    k_bnnorm<<<(N_NODES * 40 + NT - 1) / NT, NT, 0, stream>>>(
        h, aff_a, aff_c, l < NUM_LAYERS - 1 ? 1 : 0);
  }

  k_lower<<<L_SEG, NT, 0, stream>>>(h, lb, lower);
  dim3 gp(G_SEG, 2);
  k_pooled<<<gp, NT, 0, stream>>>(lower, ub, pooled);
  k_classify<<<gp, NT, 0, stream>>>(pooled, cw1, cb1, cw2, cb2, out);
}

// Round 15
// 2260.146 us; speedup vs baseline: 1.1790x; 1.1790x over previous
//
#include <hip/hip_runtime.h>

#define N_NODES 131072
#define E_EDGES 262144
#define L_SEG 16384
#define G_SEG 2048
#define D_FEAT 300
#define NUM_LAYERS 5
#define MCHUNK 65536        // GEMM row chunk (N_NODES % MCHUNK == 0; % 256 == 0)
#define HS 304              // h row stride in u16 (300 data + 4 zero pad; 608B rows)
#define KP1 320             // padded K for gemm1 (agg width)
#define KP2 608             // padded K for gemm2 (tbuf width)
#define NP1 640             // W1T rows (600 -> 640)
#define NP2 384             // W2T rows (300 -> 384)

typedef unsigned short u16;
typedef unsigned int u32;
typedef __attribute__((ext_vector_type(8))) short short8v;   // 8 bf16 = 4 VGPR
typedef __attribute__((ext_vector_type(4))) float f32x4;

struct __align__(16) U128 { u32 a, b, c, d; };
struct __align__(8) U64 { u32 a, b; };

// ---- bf16 <-> f32 helpers (RNE) ----
__device__ __forceinline__ float bf2f(u16 u) { return __uint_as_float(((u32)u) << 16); }
__device__ __forceinline__ u16 f2bf(float f) {
  u32 x = __float_as_uint(f);
  x += 0x7fffu + ((x >> 16) & 1u);
  return (u16)(x >> 16);
}
__device__ __forceinline__ u32 pack2(float x, float y) {
  return (u32)f2bf(x) | ((u32)f2bf(y) << 16);
}

// ---- async global->LDS: per-lane 16B from gptr, LDS dest = uniform base + lane*16 ----
__device__ __forceinline__ void gl2lds16(const void* g, void* l) {
  auto gp = reinterpret_cast<const __attribute__((address_space(1))) void*>(
      reinterpret_cast<uintptr_t>(g));
  auto lp = reinterpret_cast<__attribute__((address_space(3))) void*>(
      reinterpret_cast<uintptr_t>(l));
  __builtin_amdgcn_global_load_lds(gp, lp, 16, 0, 0);
}

// ---------------- h = x_emb1[x[:,0]] + x_emb2[x[:,1]]  (bf16, stride HS) ----------------
__global__ void k_init_h(const int* __restrict__ x, const float* __restrict__ e1,
                         const float* __restrict__ e2, u16* __restrict__ h) {
  int i = blockIdx.x * blockDim.x + threadIdx.x;  // N*76 ushort4 groups
  if (i >= N_NODES * 76) return;
  int n = i / 76, q = i - n * 76;
  int col = q * 4;
  ushort4 o = make_ushort4(0, 0, 0, 0);
  if (col < 300) {
    int x0 = x[2 * n], x1 = x[2 * n + 1];
    float4 va = *(const float4*)(e1 + (size_t)x0 * D_FEAT + col);
    float4 vb = *(const float4*)(e2 + (size_t)x1 * D_FEAT + col);
    o.x = f2bf(va.x + vb.x); o.y = f2bf(va.y + vb.y);
    o.z = f2bf(va.z + vb.z); o.w = f2bf(va.w + vb.w);
  }
  *(ushort4*)(h + (size_t)n * HS + col) = o;
}

// ---------------- weight prep: WT[n][k] = w[k][n], bf16, zero-padded ----------------
__global__ void k_prepw(const float* __restrict__ w, u16* __restrict__ wt,
                        int K, int Ncol, int NP, int KP) {
  int l = blockIdx.y;
  int i = blockIdx.x * blockDim.x + threadIdx.x;
  if (i >= NP * KP) return;
  int n = i / KP, k = i - n * KP;
  float v = (n < Ncol && k < K) ? w[(size_t)l * K * Ncol + (size_t)k * Ncol + n] : 0.f;
  wt[(size_t)l * NP * KP + i] = f2bf(v);
}

// ---------------- CSR build ----------------
__global__ void k_zero(float* __restrict__ p, int n) {
  int i = blockIdx.x * blockDim.x + threadIdx.x;
  if (i < n) p[i] = 0.f;
}
__global__ void k_hist(const int* __restrict__ ei, int* __restrict__ cnt) {
  int e = blockIdx.x * blockDim.x + threadIdx.x;
  if (e < E_EDGES) atomicAdd(&cnt[ei[E_EDGES + e]], 1);
}
__global__ __launch_bounds__(1024) void k_scan(const int* __restrict__ cnt,
                                               int* __restrict__ offs,
                                               int* __restrict__ cursor) {
  __shared__ int part[1024];
  int t = threadIdx.x;
  int base = t * 128;
  int s = 0;
  for (int i = 0; i < 128; i++) s += cnt[base + i];
  part[t] = s;
  __syncthreads();
  for (int off = 1; off < 1024; off <<= 1) {
    int v = (t >= off) ? part[t - off] : 0;
    __syncthreads();
    part[t] += v;
    __syncthreads();
  }
  int run = (t == 0) ? 0 : part[t - 1];
  for (int i = 0; i < 128; i++) {
    offs[base + i] = run;
    cursor[base + i] = run;
    run += cnt[base + i];
  }
  if (t == 1023) offs[N_NODES] = run;
}
__global__ void k_fill(const int* __restrict__ ei, int* __restrict__ cursor,
                       int* __restrict__ elist) {
  int e = blockIdx.x * blockDim.x + threadIdx.x;
  if (e < E_EDGES) {
    int p = atomicAdd(&cursor[ei[E_EDGES + e]], 1);
    elist[p] = e;
  }
}

// ---------------- gather-aggregate (h already normalized) ----------------
// One wave per node; edge loop unrolled 2-wide (both edges' h-rows in flight).
__global__ void k_gather(const u32* __restrict__ h, const int* __restrict__ ei,
                         const int* __restrict__ ea, const int* __restrict__ offs,
                         const int* __restrict__ elist, const float* __restrict__ sc1,
                         const float* __restrict__ sc2, const float* __restrict__ ee1,
                         const float* __restrict__ ee2, u32* __restrict__ agg) {
  int n = (blockIdx.x << 2) + (threadIdx.x >> 6);
  int lane = threadIdx.x & 63;
  int j0 = lane, j1 = lane + 64, j2 = lane + 128;  // u32 indices (data < 150)
  float ax0, ay0, ax1, ay1, ax2 = 0.f, ay2 = 0.f;
  const u32* hn = h + (size_t)n * (HS / 2);
  {
    u32 u = hn[j0];
    ax0 = bf2f((u16)(u & 0xffffu)) + sc1[2 * j0] + sc2[2 * j0];
    ay0 = bf2f((u16)(u >> 16)) + sc1[2 * j0 + 1] + sc2[2 * j0 + 1];
    u = hn[j1];
    ax1 = bf2f((u16)(u & 0xffffu)) + sc1[2 * j1] + sc2[2 * j1];
    ay1 = bf2f((u16)(u >> 16)) + sc1[2 * j1 + 1] + sc2[2 * j1 + 1];
    if (j2 < 150) {
      u = hn[j2];
      ax2 = bf2f((u16)(u & 0xffffu)) + sc1[2 * j2] + sc2[2 * j2];
      ay2 = bf2f((u16)(u >> 16)) + sc1[2 * j2 + 1] + sc2[2 * j2 + 1];
    }
  }
  int p = offs[n], pe = offs[n + 1];
  while (p + 2 <= pe) {
    int eA = elist[p], eB = elist[p + 1];
    int sA = ei[eA], sB = ei[eB];
    int a0A = ea[2 * eA], a1A = ea[2 * eA + 1];
    int a0B = ea[2 * eB], a1B = ea[2 * eB + 1];
    const u32* hA = h + (size_t)sA * (HS / 2);
    const u32* hB = h + (size_t)sB * (HS / 2);
    const float* p1A = ee1 + (size_t)a0A * D_FEAT;
    const float* p2A = ee2 + (size_t)a1A * D_FEAT;
    const float* p1B = ee1 + (size_t)a0B * D_FEAT;
    const float* p2B = ee2 + (size_t)a1B * D_FEAT;
    u32 uA0 = hA[j0], uA1 = hA[j1];
    u32 uB0 = hB[j0], uB1 = hB[j1];
    u32 uA2 = 0, uB2 = 0;
    if (j2 < 150) { uA2 = hA[j2]; uB2 = hB[j2]; }
    ax0 += bf2f((u16)(uA0 & 0xffffu)) + p1A[2 * j0] + p2A[2 * j0];
    ay0 += bf2f((u16)(uA0 >> 16)) + p1A[2 * j0 + 1] + p2A[2 * j0 + 1];
    ax1 += bf2f((u16)(uA1 & 0xffffu)) + p1A[2 * j1] + p2A[2 * j1];
    ay1 += bf2f((u16)(uA1 >> 16)) + p1A[2 * j1 + 1] + p2A[2 * j1 + 1];
    if (j2 < 150) {
      ax2 += bf2f((u16)(uA2 & 0xffffu)) + p1A[2 * j2] + p2A[2 * j2];
      ay2 += bf2f((u16)(uA2 >> 16)) + p1A[2 * j2 + 1] + p2A[2 * j2 + 1];
    }
    ax0 += bf2f((u16)(uB0 & 0xffffu)) + p1B[2 * j0] + p2B[2 * j0];
    ay0 += bf2f((u16)(uB0 >> 16)) + p1B[2 * j0 + 1] + p2B[2 * j0 + 1];
    ax1 += bf2f((u16)(uB1 & 0xffffu)) + p1B[2 * j1] + p2B[2 * j1];
    ay1 += bf2f((u16)(uB1 >> 16)) + p1B[2 * j1 + 1] + p2B[2 * j1 + 1];
    if (j2 < 150) {
      ax2 += bf2f((u16)(uB2 & 0xffffu)) + p1B[2 * j2] + p2B[2 * j2];
      ay2 += bf2f((u16)(uB2 >> 16)) + p1B[2 * j2 + 1] + p2B[2 * j2 + 1];
    }
    p += 2;
  }
  if (p < pe) {  // tail edge
    int e = elist[p];
    int s = ei[e];
    int a0 = ea[2 * e], a1 = ea[2 * e + 1];
    const u32* hs = h + (size_t)s * (HS / 2);
    const float* p1 = ee1 + (size_t)a0 * D_FEAT;
    const float* p2 = ee2 + (size_t)a1 * D_FEAT;
    u32 u = hs[j0];
    ax0 += bf2f((u16)(u & 0xffffu)) + p1[2 * j0] + p2[2 * j0];
    ay0 += bf2f((u16)(u >> 16)) + p1[2 * j0 + 1] + p2[2 * j0 + 1];
    u = hs[j1];
    ax1 += bf2f((u16)(u & 0xffffu)) + p1[2 * j1] + p2[2 * j1];
    ay1 += bf2f((u16)(u >> 16)) + p1[2 * j1 + 1] + p2[2 * j1 + 1];
    if (j2 < 150) {
      u = hs[j2];
      ax2 += bf2f((u16)(u & 0xffffu)) + p1[2 * j2] + p2[2 * j2];
      ay2 += bf2f((u16)(u >> 16)) + p1[2 * j2 + 1] + p2[2 * j2 + 1];
    }
  }
  u32* ao = agg + (size_t)n * (KP1 / 2);
  ao[j0] = pack2(ax0, ay0);
  ao[j1] = pack2(ax1, ay1);
  if (j2 < 150) ao[j2] = pack2(ax2, ay2);
  else if (j2 < 160) ao[j2] = 0u;
}

// ---------------- MFMA GEMM: C = A@W^T + bias, opt relu, opt fused col-stats ----------------
// 256x128 tile, 8 waves (512 thr), BK=32, 3-DEEP pipelined fragment-ordered LDS
// with COUNTED vmcnt (T4): per step, s_waitcnt vmcnt(3) waits only the 2-step-old
// load batch (3 gl2lds/wave = one batch); raw s_barrier (no vmcnt(0) drain);
// then issue step i+2's loads; compute step i. vmcnt(0) only at the last step.
// Safety: sched_barrier(0) after waits/barrier pins ordering (rules #18/m152);
// readers of a buffer consume via MFMA (lgkm-waited) before reaching the next
// barrier, so overwriting that buffer after the barrier cannot race.
// Buffers: 3 x 12288 u16 (24KB) = 72KB LDS -> 2 blocks/CU.
// Block m of A (16 blocks) at buf+m*512; B block w at buf+8192+w*512; slot
// l <-> (row m*16+(l&15), k-chunk l>>4) at base + l*16B (conflict-free reads).
// Epilogue (unchanged): 4 passes of 64 rows via LDS [64][132], 8B coalesced
// stores, optional fused per-column sum/sumsq (stats[0..303], stats[304..607]).
template <bool RELU, int KP>
__global__ __launch_bounds__(512) void k_gemm_mfma(const u16* __restrict__ A,
                                                   const u16* __restrict__ WT,
                                                   const float* __restrict__ bias,
                                                   u16* __restrict__ C, int Ncol,
                                                   int Cstride, float* __restrict__ stats) {
  __shared__ __align__(16) u16 SL[36864];  // 72KB: 3 bufs of 12288 u16
  int t = threadIdx.x;
  int w = t >> 6, lane = t & 63;
  int brow = blockIdx.y << 8, bcol = blockIdx.x << 7;
  int wr = w >> 1, wc = w & 1;
  int r16 = lane & 15, kq = lane >> 4;
  int rq = kq << 2;

  f32x4 zero4 = {0.f, 0.f, 0.f, 0.f};
  f32x4 acc[4][4];
#pragma unroll
  for (int mi = 0; mi < 4; mi++)
#pragma unroll
    for (int nj = 0; nj < 4; nj++) acc[mi][nj] = zero4;

  int m0 = 2 * w, m1 = m0 + 1;
  const u16* gA0 = A + (size_t)(brow + m0 * 16 + r16) * KP + kq * 8;
  const u16* gA1 = A + (size_t)(brow + m1 * 16 + r16) * KP + kq * 8;
  const u16* gB = WT + (size_t)(bcol + w * 16 + r16) * KP + kq * 8;

  // prologue: issue batches L0 (buf0) and L1 (buf1)
  gl2lds16(gA0, SL + m0 * 512);
  gl2lds16(gA1, SL + m1 * 512);
  gl2lds16(gB, SL + 8192 + w * 512);
  if (KP > 32) {
    gl2lds16(gA0 + 32, SL + 12288 + m0 * 512);
    gl2lds16(gA1 + 32, SL + 12288 + m1 * 512);
    gl2lds16(gB + 32, SL + 12288 + 8192 + w * 512);
  }

  int bi = 0;
  for (int k0 = 0; k0 < KP; k0 += 32) {
    // wait for THIS step's batch only (one newer batch may stay in flight)
    if (k0 + 32 < KP) {
      asm volatile("s_waitcnt vmcnt(3)" ::: "memory");
    } else {
      asm volatile("s_waitcnt vmcnt(0)" ::: "memory");
    }
    __builtin_amdgcn_sched_barrier(0);
    __builtin_amdgcn_s_barrier();       // all waves' step-i data now in LDS
    __builtin_amdgcn_sched_barrier(0);
    if (k0 + 64 < KP) {                 // issue L(i+2) into the buffer read at step i-1
      int nb = bi + 2;
      nb = (nb >= 3) ? nb - 3 : nb;
      u16* nxtb = SL + nb * 12288;
      gl2lds16(gA0 + k0 + 64, nxtb + m0 * 512);
      gl2lds16(gA1 + k0 + 64, nxtb + m1 * 512);
      gl2lds16(gB + k0 + 64, nxtb + 8192 + w * 512);
    }
    u16* curb = SL + bi * 12288;
    short8v af[4], bf[4];
#pragma unroll
    for (int mi = 0; mi < 4; mi++)
      af[mi] = *(const short8v*)(curb + (wr * 4 + mi) * 512 + lane * 8);
#pragma unroll
    for (int nj = 0; nj < 4; nj++)
      bf[nj] = *(const short8v*)(curb + 8192 + (wc * 4 + nj) * 512 + lane * 8);
#pragma unroll
    for (int mi = 0; mi < 4; mi++)
#pragma unroll
      for (int nj = 0; nj < 4; nj++)
        acc[mi][nj] = __builtin_amdgcn_mfma_f32_16x16x32_bf16(af[mi], bf[nj], acc[mi][nj], 0, 0, 0);
    bi = (bi == 2) ? 0 : bi + 1;
  }
  __builtin_amdgcn_sched_barrier(0);
  __syncthreads();  // full drain once before SL is repurposed

  // ---- epilogue: 4 passes of 64 rows via LDS [64][132] u16, 8B coalesced stores ----
#pragma unroll
  for (int p = 0; p < 4; p++) {
    if (wr == p) {
#pragma unroll
      for (int nj = 0; nj < 4; nj++) {
        int col = wc * 64 + nj * 16 + r16;
        int gcol = bcol + col;
        bool live = gcol < Ncol;
        float bs = live ? bias[gcol] : 0.f;
#pragma unroll
        for (int mi = 0; mi < 4; mi++) {
#pragma unroll
          for (int jj = 0; jj < 4; jj++) {
            float v = acc[mi][nj][jj] + bs;   // D row = (lane>>4)*4+jj, col = lane&15
            if (RELU) v = fmaxf(v, 0.f);
            if (!live) v = 0.f;
            SL[(mi * 16 + rq + jj) * 132 + col] = f2bf(v);
          }
        }
      }
    }
    __syncthreads();
    {
      int r = t >> 3, s = t & 7;  // row 0..63, col-oct 0..7
      size_t grow = (size_t)(brow + p * 64 + r) * Cstride;
#pragma unroll
      for (int c = 0; c < 2; c++) {
        int colu = s * 16 + c * 8;
        int gcol = bcol + colu;
        if (gcol + 8 <= Cstride) {
          U64 v0 = *(const U64*)(SL + r * 132 + colu);
          U64 v1 = *(const U64*)(SL + r * 132 + colu + 4);
          *(U64*)(C + grow + gcol) = v0;
          *(U64*)(C + grow + gcol + 4) = v1;
        }
      }
    }
    // fused column stats over this pass's 64 rows (bf16 bits == what h stores)
    if (stats != nullptr && t < 128) {
      int gcol = bcol + t;
      if (gcol < Ncol) {
        float s0 = 0.f, q0 = 0.f;
#pragma unroll 8
        for (int r = 0; r < 64; r++) {
          float v = bf2f(SL[r * 132 + t]);
          s0 += v;
          q0 = fmaf(v, v, q0);
        }
        atomicAdd(stats + gcol, s0);
        atomicAdd(stats + 304 + gcol, q0);
      }
    }
    __syncthreads();
  }
}

// ---------------- BN finalize: a = rsqrt(var+eps)*gamma, c = beta - mu*a (pads -> 0) ----------------
__global__ void k_bnfin(const float* __restrict__ sums, const float* __restrict__ gamma,
                        const float* __restrict__ beta, float* __restrict__ fa,
                        float* __restrict__ fc) {
  int d = blockIdx.x * blockDim.x + threadIdx.x;
  if (d >= HS) return;
  float a = 0.f, c = 0.f;
  if (d < D_FEAT) {
    const float inv = 1.f / (float)N_NODES;
    float mu = sums[d] * inv;
    float var = sums[304 + d] * inv - mu * mu;
    a = rsqrtf(var + 1e-5f) * gamma[d];
    c = beta[d] - mu * a;
  }
  fa[d] = a;
  fc[d] = c;
}

// ---------------- BN normalize (+opt relu), 8-wide, in place on bf16 (stride HS) ----------------
__global__ void k_bnnorm(u16* __restrict__ h, const float* __restrict__ fa,
                         const float* __restrict__ fc, int relu) {
  int i = blockIdx.x * blockDim.x + threadIdx.x;  // N*38 groups of 8
  if (i >= N_NODES * 38) return;
  int n = i / 38, q = i - n * 38;
  int col = q * 8;
  u16* hp = h + (size_t)n * HS + col;
  float4 a0 = *(const float4*)(fa + col);
  float4 a1 = *(const float4*)(fa + col + 4);
  float4 c0 = *(const float4*)(fc + col);
  float4 c1 = *(const float4*)(fc + col + 4);
  ushort4 u0 = *(ushort4*)hp;
  ushort4 u1 = *(ushort4*)(hp + 4);
  float r0, r1, r2, r3, r4, r5, r6, r7;
#define BN1(res, uv, A, C)                       \
  res = fmaf((A), bf2f(uv), (C));                \
  if (relu) res = fmaxf(res, 0.f);
  BN1(r0, u0.x, a0.x, c0.x) BN1(r1, u0.y, a0.y, c0.y)
  BN1(r2, u0.z, a0.z, c0.z) BN1(r3, u0.w, a0.w, c0.w)
  BN1(r4, u1.x, a1.x, c1.x) BN1(r5, u1.y, a1.y, c1.y)
  BN1(r6, u1.z, a1.z, c1.z) BN1(r7, u1.w, a1.w, c1.w)
#undef BN1
  ushort4 o0, o1;
  o0.x = f2bf(r0); o0.y = f2bf(r1); o0.z = f2bf(r2); o0.w = f2bf(r3);
  o1.x = f2bf(r4); o1.y = f2bf(r5); o1.z = f2bf(r6); o1.w = f2bf(r7);
  *(ushort4*)hp = o0;
  *(ushort4*)(hp + 4) = o1;
}

// ---------------- segment means (sorted ids, binary search) ----------------
__device__ __forceinline__ int lowerBound(const int* __restrict__ a, int n, int v) {
  int lo = 0, hi = n;
  while (lo < hi) {
    int m = (lo + hi) >> 1;
    if (a[m] < v) lo = m + 1; else hi = m;
  }
  return lo;
}

__global__ void k_lower(const u16* __restrict__ h, const int* __restrict__ lb,
                        float* __restrict__ lower) {
  int g = blockIdx.x;
  int s = lowerBound(lb, N_NODES, g);
  int e = lowerBound(lb, N_NODES, g + 1);
  float invc = 1.f / (float)max(e - s, 1);
  for (int d = threadIdx.x; d < D_FEAT; d += 256) {
    float acc = 0.f;
    for (int r = s; r < e; r++) acc += bf2f(h[(size_t)r * HS + d]);
    lower[(size_t)g * D_FEAT + d] = acc * invc;
  }
}

__global__ void k_pooled(const float* __restrict__ lower, const int* __restrict__ ub,
                         float* __restrict__ pooled) {
  int g = blockIdx.x, br = blockIdx.y;
  int s = lowerBound(ub, L_SEG, g);
  int e = lowerBound(ub, L_SEG, g + 1);
  float invc = 1.f / (float)max(e - s, 1);
  for (int d = threadIdx.x; d < D_FEAT; d += 256) {
    float acc = 0.f;
    for (int i = s; i < e; i++) {
      int row = br ? (i - 1 + L_SEG) % L_SEG : i;
      acc += lower[(size_t)row * D_FEAT + d];
    }
    pooled[((size_t)br * G_SEG + g) * D_FEAT + d] = acc * invc;
  }
}

__global__ __launch_bounds__(256) void k_classify(const float* __restrict__ pooled,
                                                  const float* __restrict__ w1,
                                                  const float* __restrict__ b1,
                                                  const float* __restrict__ w2,
                                                  const float* __restrict__ b2,
                                                  float* __restrict__ out) {
  __shared__ float p[D_FEAT];
  __shared__ float red[4];
  int g = blockIdx.x, br = blockIdx.y;
  const float* pr = pooled + ((size_t)br * G_SEG + g) * D_FEAT;
  for (int d = threadIdx.x; d < D_FEAT; d += 256) p[d] = pr[d];
  __syncthreads();
  float partial = 0.f;
  for (int j = threadIdx.x; j < D_FEAT; j += 256) {
    float acc = b1[j];
    for (int k = 0; k < D_FEAT; k++) acc = fmaf(p[k], w1[(size_t)k * D_FEAT + j], acc);
    acc = fmaxf(acc, 0.f);
    partial += acc * w2[j];
  }
  for (int off = 32; off; off >>= 1) partial += __shfl_down(partial, off, 64);
  int lane = threadIdx.x & 63, wid = threadIdx.x >> 6;
  if (lane == 0) red[wid] = partial;
  __syncthreads();
  if (threadIdx.x == 0) out[(size_t)br * G_SEG + g] = red[0] + red[1] + red[2] + red[3] + b2[0];
}

extern "C" void kernel_launch(void* const* d_in, const int* in_sizes, int n_in,
                              void* d_out, int out_size, void* d_ws, size_t ws_size,
                              hipStream_t stream) {
  const int* x = (const int*)d_in[0];
  const int* ei = (const int*)d_in[1];
  const int* ea = (const int*)d_in[2];
  const int* lb = (const int*)d_in[3];
  const int* ub = (const int*)d_in[4];
  const float* xe1 = (const float*)d_in[5];
  const float* xe2 = (const float*)d_in[6];
  const float* ee1 = (const float*)d_in[7];
  const float* ee2 = (const float*)d_in[8];
  const float* w1 = (const float*)d_in[9];
  const float* b1 = (const float*)d_in[10];
  const float* w2 = (const float*)d_in[11];
  const float* b2 = (const float*)d_in[12];
  const float* gam = (const float*)d_in[13];
  const float* bet = (const float*)d_in[14];
  const float* cw1 = (const float*)d_in[15];
  const float* cb1 = (const float*)d_in[16];
  const float* cw2 = (const float*)d_in[17];
  const float* cb2 = (const float*)d_in[18];
  float* out = (float*)d_out;

  // ---- workspace (~248 MB; known-safe >= 255.59 MB from R3 tier-B) ----
  char* base = (char*)d_ws;
  size_t off = 0;
  auto alloc = [&](size_t bytes) -> void* {
    void* p = base + off;
    off += (bytes + 255) & ~(size_t)255;
    return p;
  };
  u16* h = (u16*)alloc((size_t)N_NODES * HS * 2);            // 79.7 MB
  u16* agg = (u16*)alloc((size_t)N_NODES * KP1 * 2);         // 83.9 MB
  u16* tbuf = (u16*)alloc((size_t)MCHUNK * KP2 * 2);         // 79.7 MB
  u16* W1T = (u16*)alloc((size_t)NUM_LAYERS * NP1 * KP1 * 2);
  u16* W2T = (u16*)alloc((size_t)NUM_LAYERS * NP2 * KP2 * 2);
  int* cnt = (int*)alloc((size_t)N_NODES * 4);
  int* offs = (int*)alloc((size_t)(N_NODES + 1) * 4);
  int* cursor = (int*)alloc((size_t)N_NODES * 4);
  int* elist = (int*)alloc((size_t)E_EDGES * 4);
  float* stats = (float*)alloc(608 * 4);   // sum[0..303], sumsq[304..607]
  float* aff_a = (float*)alloc(HS * 4);
  float* aff_c = (float*)alloc(HS * 4);
  float* lower = (float*)tbuf;                               // alias (post-loop only)
  float* pooled = lower + (size_t)L_SEG * D_FEAT;

  if (ws_size < off) {
    k_zero<<<(out_size + 255) / 256, 256, 0, stream>>>(out, out_size);
    return;
  }

  const int NT = 256;

  k_prepw<<<dim3((NP1 * KP1 + NT - 1) / NT, NUM_LAYERS), NT, 0, stream>>>(w1, W1T, 300, 600, NP1, KP1);
  k_prepw<<<dim3((NP2 * KP2 + NT - 1) / NT, NUM_LAYERS), NT, 0, stream>>>(w2, W2T, 600, 300, NP2, KP2);

  k_zero<<<(N_NODES + NT - 1) / NT, NT, 0, stream>>>((float*)cnt, N_NODES);
  k_hist<<<(E_EDGES + NT - 1) / NT, NT, 0, stream>>>(ei, cnt);
  k_scan<<<1, 1024, 0, stream>>>(cnt, offs, cursor);
  k_fill<<<(E_EDGES + NT - 1) / NT, NT, 0, stream>>>(ei, cursor, elist);

  k_init_h<<<(N_NODES * 76 + NT - 1) / NT, NT, 0, stream>>>(x, xe1, xe2, h);

  for (int l = 0; l < NUM_LAYERS; l++) {
    k_gather<<<N_NODES / 4, NT, 0, stream>>>(
        (const u32*)h, ei, ea, offs, elist,
        ee1 + ((size_t)l * 6 + 4) * D_FEAT, ee2 + (size_t)l * 3 * D_FEAT,
        ee1 + (size_t)l * 6 * D_FEAT, ee2 + (size_t)l * 3 * D_FEAT, (u32*)agg);
    k_zero<<<3, NT, 0, stream>>>(stats, 608);
    for (int c0 = 0; c0 < N_NODES; c0 += MCHUNK) {
      dim3 g1(5, MCHUNK / 256);
      k_gemm_mfma<true, KP1><<<g1, 512, 0, stream>>>(
          agg + (size_t)c0 * KP1, W1T + (size_t)l * NP1 * KP1, b1 + (size_t)l * 600,
          tbuf, 600, KP2, nullptr);
      dim3 g2(3, MCHUNK / 256);
      k_gemm_mfma<false, KP2><<<g2, 512, 0, stream>>>(
          tbuf, W2T + (size_t)l * NP2 * KP2, b2 + (size_t)l * 300,
          h + (size_t)c0 * HS, 300, HS, stats);
    }
    k_bnfin<<<2, NT, 0, stream>>>(stats, gam + (size_t)l * 300, bet + (size_t)l * 300,
                                  aff_a, aff_c);
    k_bnnorm<<<(N_NODES * 38 + NT - 1) / NT, NT, 0, stream>>>(
        h, aff_a, aff_c, l < NUM_LAYERS - 1 ? 1 : 0);
  }

  k_lower<<<L_SEG, NT, 0, stream>>>(h, lb, lower);
  dim3 gp(G_SEG, 2);
  k_pooled<<<gp, NT, 0, stream>>>(lower, ub, pooled);
  k_classify<<<gp, NT, 0, stream>>>(pooled, cw1, cb1, cw2, cb2, out);
}

// Round 19
// 2244.975 us; speedup vs baseline: 1.1870x; 1.0068x over previous
//
#include <hip/hip_runtime.h>

#define N_NODES 131072
#define E_EDGES 262144
#define L_SEG 16384
#define G_SEG 2048
#define D_FEAT 300
#define NUM_LAYERS 5
#define HS 304              // h row stride in u16 (300 data + 4 zero pad; 608B rows)
#define KP1 320             // padded K for phase 1 (agg width)
#define KP2 608             // padded K for phase 2 (T width); 19 k-steps of 32
#define NB1 40              // W1 col frag-blocks (640 cols)
#define NK1 10              // W1 k-steps (320/32)
#define NB2 24              // W2 col frag-blocks (384 cols)
#define NK2 19              // W2 k-steps (608/32)

typedef unsigned short u16;
typedef unsigned int u32;
typedef __attribute__((ext_vector_type(8))) short short8v;   // 8 bf16 = 4 VGPR
typedef __attribute__((ext_vector_type(4))) float f32x4;

struct __align__(16) U128 { u32 a, b, c, d; };   // 16B = 8 u16
struct __align__(8) U64 { u32 a, b; };           // 8B = 4 u16 (NOT 8! R16/R18 bug)

// ---- bf16 <-> f32 helpers (RNE) ----
__device__ __forceinline__ float bf2f(u16 u) { return __uint_as_float(((u32)u) << 16); }
__device__ __forceinline__ u16 f2bf(float f) {
  u32 x = __float_as_uint(f);
  x += 0x7fffu + ((x >> 16) & 1u);
  return (u16)(x >> 16);
}
__device__ __forceinline__ u32 pack2(float x, float y) {
  return (u32)f2bf(x) | ((u32)f2bf(y) << 16);
}

// ---------------- h = x_emb1[x[:,0]] + x_emb2[x[:,1]]  (bf16, stride HS) ----------------
__global__ void k_init_h(const int* __restrict__ x, const float* __restrict__ e1,
                         const float* __restrict__ e2, u16* __restrict__ h) {
  int i = blockIdx.x * blockDim.x + threadIdx.x;  // N*76 ushort4 groups
  if (i >= N_NODES * 76) return;
  int n = i / 76, q = i - n * 76;
  int col = q * 4;
  ushort4 o = make_ushort4(0, 0, 0, 0);
  if (col < 300) {
    int x0 = x[2 * n], x1 = x[2 * n + 1];
    float4 va = *(const float4*)(e1 + (size_t)x0 * D_FEAT + col);
    float4 vb = *(const float4*)(e2 + (size_t)x1 * D_FEAT + col);
    o.x = f2bf(va.x + vb.x); o.y = f2bf(va.y + vb.y);
    o.z = f2bf(va.z + vb.z); o.w = f2bf(va.w + vb.w);
  }
  *(ushort4*)(h + (size_t)n * HS + col) = o;
}

// ---------------- weight pack: fragment-ordered bf16 frags ----------------
// wp block (nb, ks) = 512 u16: slot l (0..63) x 8: n = nb*16+(l&15), k = ks*32+(l>>4)*8+c.
__global__ void k_packw(const float* __restrict__ w, u16* __restrict__ wp,
                        int K, int Ncol, int NB, int NK) {
  int l = blockIdx.y;
  int i = blockIdx.x * blockDim.x + threadIdx.x;
  int tot = NB * NK * 512;
  if (i >= tot) return;
  int nb = i / (NK * 512);
  int r = i - nb * (NK * 512);
  int ks = r / 512;
  int s = r - ks * 512;
  int lane2 = s >> 3, c = s & 7;
  int n = nb * 16 + (lane2 & 15);
  int k = ks * 32 + (lane2 >> 4) * 8 + c;
  float v = (n < Ncol && k < K) ? w[(size_t)l * K * Ncol + (size_t)k * Ncol + n] : 0.f;
  wp[(size_t)l * tot + i] = f2bf(v);
}

// ---------------- CSR build ----------------
__global__ void k_zero(float* __restrict__ p, int n) {
  int i = blockIdx.x * blockDim.x + threadIdx.x;
  if (i < n) p[i] = 0.f;
}
__global__ void k_hist(const int* __restrict__ ei, int* __restrict__ cnt) {
  int e = blockIdx.x * blockDim.x + threadIdx.x;
  if (e < E_EDGES) atomicAdd(&cnt[ei[E_EDGES + e]], 1);
}
__global__ __launch_bounds__(1024) void k_scan(const int* __restrict__ cnt,
                                               int* __restrict__ offs,
                                               int* __restrict__ cursor) {
  __shared__ int part[1024];
  int t = threadIdx.x;
  int base = t * 128;
  int s = 0;
  for (int i = 0; i < 128; i++) s += cnt[base + i];
  part[t] = s;
  __syncthreads();
  for (int off = 1; off < 1024; off <<= 1) {
    int v = (t >= off) ? part[t - off] : 0;
    __syncthreads();
    part[t] += v;
    __syncthreads();
  }
  int run = (t == 0) ? 0 : part[t - 1];
  for (int i = 0; i < 128; i++) {
    offs[base + i] = run;
    cursor[base + i] = run;
    run += cnt[base + i];
  }
  if (t == 1023) offs[N_NODES] = run;
}
__global__ void k_fill(const int* __restrict__ ei, int* __restrict__ cursor,
                       int* __restrict__ elist) {
  int e = blockIdx.x * blockDim.x + threadIdx.x;
  if (e < E_EDGES) {
    int p = atomicAdd(&cursor[ei[E_EDGES + e]], 1);
    elist[p] = e;
  }
}

// ---------------- gather-aggregate (h already normalized) ----------------
__global__ void k_gather(const u32* __restrict__ h, const int* __restrict__ ei,
                         const int* __restrict__ ea, const int* __restrict__ offs,
                         const int* __restrict__ elist, const float* __restrict__ sc1,
                         const float* __restrict__ sc2, const float* __restrict__ ee1,
                         const float* __restrict__ ee2, u32* __restrict__ agg) {
  int n = (blockIdx.x << 2) + (threadIdx.x >> 6);
  int lane = threadIdx.x & 63;
  int j0 = lane, j1 = lane + 64, j2 = lane + 128;  // u32 indices (data < 150)
  float ax0, ay0, ax1, ay1, ax2 = 0.f, ay2 = 0.f;
  const u32* hn = h + (size_t)n * (HS / 2);
  {
    u32 u = hn[j0];
    ax0 = bf2f((u16)(u & 0xffffu)) + sc1[2 * j0] + sc2[2 * j0];
    ay0 = bf2f((u16)(u >> 16)) + sc1[2 * j0 + 1] + sc2[2 * j0 + 1];
    u = hn[j1];
    ax1 = bf2f((u16)(u & 0xffffu)) + sc1[2 * j1] + sc2[2 * j1];
    ay1 = bf2f((u16)(u >> 16)) + sc1[2 * j1 + 1] + sc2[2 * j1 + 1];
    if (j2 < 150) {
      u = hn[j2];
      ax2 = bf2f((u16)(u & 0xffffu)) + sc1[2 * j2] + sc2[2 * j2];
      ay2 = bf2f((u16)(u >> 16)) + sc1[2 * j2 + 1] + sc2[2 * j2 + 1];
    }
  }
  int p = offs[n], pe = offs[n + 1];
  while (p + 2 <= pe) {
    int eA = elist[p], eB = elist[p + 1];
    int sA = ei[eA], sB = ei[eB];
    int a0A = ea[2 * eA], a1A = ea[2 * eA + 1];
    int a0B = ea[2 * eB], a1B = ea[2 * eB + 1];
    const u32* hA = h + (size_t)sA * (HS / 2);
    const u32* hB = h + (size_t)sB * (HS / 2);
    const float* p1A = ee1 + (size_t)a0A * D_FEAT;
    const float* p2A = ee2 + (size_t)a1A * D_FEAT;
    const float* p1B = ee1 + (size_t)a0B * D_FEAT;
    const float* p2B = ee2 + (size_t)a1B * D_FEAT;
    u32 uA0 = hA[j0], uA1 = hA[j1];
    u32 uB0 = hB[j0], uB1 = hB[j1];
    u32 uA2 = 0, uB2 = 0;
    if (j2 < 150) { uA2 = hA[j2]; uB2 = hB[j2]; }
    ax0 += bf2f((u16)(uA0 & 0xffffu)) + p1A[2 * j0] + p2A[2 * j0];
    ay0 += bf2f((u16)(uA0 >> 16)) + p1A[2 * j0 + 1] + p2A[2 * j0 + 1];
    ax1 += bf2f((u16)(uA1 & 0xffffu)) + p1A[2 * j1] + p2A[2 * j1];
    ay1 += bf2f((u16)(uA1 >> 16)) + p1A[2 * j1 + 1] + p2A[2 * j1 + 1];
    if (j2 < 150) {
      ax2 += bf2f((u16)(uA2 & 0xffffu)) + p1A[2 * j2] + p2A[2 * j2];
      ay2 += bf2f((u16)(uA2 >> 16)) + p1A[2 * j2 + 1] + p2A[2 * j2 + 1];
    }
    ax0 += bf2f((u16)(uB0 & 0xffffu)) + p1B[2 * j0] + p2B[2 * j0];
    ay0 += bf2f((u16)(uB0 >> 16)) + p1B[2 * j0 + 1] + p2B[2 * j0 + 1];
    ax1 += bf2f((u16)(uB1 & 0xffffu)) + p1B[2 * j1] + p2B[2 * j1];
    ay1 += bf2f((u16)(uB1 >> 16)) + p1B[2 * j1 + 1] + p2B[2 * j1 + 1];
    if (j2 < 150) {
      ax2 += bf2f((u16)(uB2 & 0xffffu)) + p1B[2 * j2] + p2B[2 * j2];
      ay2 += bf2f((u16)(uB2 >> 16)) + p1B[2 * j2 + 1] + p2B[2 * j2 + 1];
    }
    p += 2;
  }
  if (p < pe) {  // tail edge
    int e = elist[p];
    int s = ei[e];
    int a0 = ea[2 * e], a1 = ea[2 * e + 1];
    const u32* hs = h + (size_t)s * (HS / 2);
    const float* p1 = ee1 + (size_t)a0 * D_FEAT;
    const float* p2 = ee2 + (size_t)a1 * D_FEAT;
    u32 u = hs[j0];
    ax0 += bf2f((u16)(u & 0xffffu)) + p1[2 * j0] + p2[2 * j0];
    ay0 += bf2f((u16)(u >> 16)) + p1[2 * j0 + 1] + p2[2 * j0 + 1];
    u = hs[j1];
    ax1 += bf2f((u16)(u & 0xffffu)) + p1[2 * j1] + p2[2 * j1];
    ay1 += bf2f((u16)(u >> 16)) + p1[2 * j1 + 1] + p2[2 * j1 + 1];
    if (j2 < 150) {
      u = hs[j2];
      ax2 += bf2f((u16)(u & 0xffffu)) + p1[2 * j2] + p2[2 * j2];
      ay2 += bf2f((u16)(u >> 16)) + p1[2 * j2 + 1] + p2[2 * j2 + 1];
    }
  }
  u32* ao = agg + (size_t)n * (KP1 / 2);
  ao[j0] = pack2(ax0, ay0);
  ao[j1] = pack2(ax1, ay1);
  if (j2 < 150) ao[j2] = pack2(ax2, ay2);
  else if (j2 < 160) ao[j2] = 0u;
}

// ---------------- FUSED MLP: h = relu(agg@W1+b1)@W2+b2 (one dispatch/layer) --------------
// R16 structure with the U64->U128 h-store fix (U64 is 4 u16; chunks are 8 u16).
// Block = 512 thr (8 waves), 64 rows. Phase 1 (64x640, K=320): A-frags from global
// agg, B-frags from fragment-packed W1P (L2-resident). No barriers. T -> LDS in
// phase-2 fragment order. Phase 2 (64x384, K=608): A from LDS, B from packed W2P.
// Epilogue: LDS-staged coalesced h-store + fused column stats.
__global__ __launch_bounds__(512) void k_mlp(const u16* __restrict__ agg,
                                             const u16* __restrict__ W1P,
                                             const float* __restrict__ b1,
                                             const u16* __restrict__ W2P,
                                             const float* __restrict__ b2,
                                             u16* __restrict__ h,
                                             float* __restrict__ stats) {
  __shared__ __align__(16) u16 TL[4 * NK2 * 512];  // 38912 u16 = 76KB; HT aliases
  int t = threadIdx.x;
  int w = t >> 6, lane = t & 63;
  int wr = w >> 2, wc = w & 3;
  int r16 = lane & 15, kq = lane >> 4, rq = kq << 2;
  int brow = blockIdx.x << 6;

  f32x4 zero4 = {0.f, 0.f, 0.f, 0.f};

  // ---- phase 1 ----
  f32x4 acc1[2][10];
#pragma unroll
  for (int fr = 0; fr < 2; fr++)
#pragma unroll
    for (int fc = 0; fc < 10; fc++) acc1[fr][fc] = zero4;

  const u16* Ab = agg + (size_t)(brow + wr * 32 + r16) * KP1 + kq * 8;
  const u16* W1w = W1P + (size_t)(wc * 10) * NK1 * 512 + lane * 8;
  for (int ks = 0; ks < NK1; ks++) {
    short8v af0 = *(const short8v*)(Ab + ks * 32);
    short8v af1 = *(const short8v*)(Ab + 16 * KP1 + ks * 32);
#pragma unroll
    for (int fc = 0; fc < 10; fc++) {
      short8v bf = *(const short8v*)(W1w + (size_t)(fc * NK1 + ks) * 512);
      acc1[0][fc] = __builtin_amdgcn_mfma_f32_16x16x32_bf16(af0, bf, acc1[0][fc], 0, 0, 0);
      acc1[1][fc] = __builtin_amdgcn_mfma_f32_16x16x32_bf16(af1, bf, acc1[1][fc], 0, 0, 0);
    }
  }

  // write T = relu(acc1 + b1) into TL, phase-2 fragment order
#pragma unroll
  for (int fc = 0; fc < 10; fc++) {
    int col = wc * 160 + fc * 16 + r16;
    if (col < KP2) {  // cols 608..639 dropped (zero contribution)
      float bs = (col < 600) ? b1[col] : 0.f;
      int ks2 = wc * 5 + (fc >> 1);
      int coff = (((fc & 1) * 2 + (r16 >> 3)) * 16) * 8 + (r16 & 7);
#pragma unroll
      for (int fr = 0; fr < 2; fr++) {
        u16* blk = TL + (size_t)((wr * 2 + fr) * NK2 + ks2) * 512;
#pragma unroll
        for (int j = 0; j < 4; j++) {
          float v = fmaxf(acc1[fr][fc][j] + bs, 0.f);
          blk[coff + (rq + j) * 8] = f2bf(v);
        }
      }
    }
  }
  __syncthreads();  // T complete

  // ---- phase 2 ----
  f32x4 acc2[2][6];
#pragma unroll
  for (int fr = 0; fr < 2; fr++)
#pragma unroll
    for (int fc = 0; fc < 6; fc++) acc2[fr][fc] = zero4;

  const u16* W2w = W2P + (size_t)(wc * 6) * NK2 * 512 + lane * 8;
  for (int ks = 0; ks < NK2; ks++) {
    short8v af0 = *(const short8v*)(TL + (size_t)((wr * 2 + 0) * NK2 + ks) * 512 + lane * 8);
    short8v af1 = *(const short8v*)(TL + (size_t)((wr * 2 + 1) * NK2 + ks) * 512 + lane * 8);
#pragma unroll
    for (int fc = 0; fc < 6; fc++) {
      short8v bf = *(const short8v*)(W2w + (size_t)(fc * NK2 + ks) * 512);
      acc2[0][fc] = __builtin_amdgcn_mfma_f32_16x16x32_bf16(af0, bf, acc2[0][fc], 0, 0, 0);
      acc2[1][fc] = __builtin_amdgcn_mfma_f32_16x16x32_bf16(af1, bf, acc2[1][fc], 0, 0, 0);
    }
  }
  __syncthreads();  // all TL reads done; reuse as HT[64][392]

  u16* HT = TL;
#pragma unroll
  for (int fc = 0; fc < 6; fc++) {
    int col = wc * 96 + fc * 16 + r16;
    bool live = col < 300;
    float bs = live ? b2[col] : 0.f;
#pragma unroll
    for (int fr = 0; fr < 2; fr++) {
      int row = wr * 32 + fr * 16 + rq;
#pragma unroll
      for (int j = 0; j < 4; j++) {
        float v = acc2[fr][fc][j] + bs;
        if (!live) v = 0.f;
        HT[(size_t)(row + j) * 392 + col] = f2bf(v);
      }
    }
  }
  __syncthreads();

  // coalesced h store: 64 rows x 304 u16 = 38 U128 chunks/row (U128 = 8 u16; FIX)
  for (int i = t; i < 64 * 38; i += 512) {
    int r = i / 38, c8 = (i - r * 38) * 8;
    U128 v = *(const U128*)(HT + (size_t)r * 392 + c8);
    *(U128*)(h + (size_t)(brow + r) * HS + c8) = v;
  }
  // fused column stats over the 64 rows (bf16 bits == what h stores)
  if (t < 300) {
    float s0 = 0.f, q0 = 0.f;
#pragma unroll 8
    for (int r = 0; r < 64; r++) {
      float v = bf2f(HT[(size_t)r * 392 + t]);
      s0 += v;
      q0 = fmaf(v, v, q0);
    }
    atomicAdd(stats + t, s0);
    atomicAdd(stats + 304 + t, q0);
  }
}

// ---------------- BN finalize: a = rsqrt(var+eps)*gamma, c = beta - mu*a (pads -> 0) ----------------
__global__ void k_bnfin(const float* __restrict__ sums, const float* __restrict__ gamma,
                        const float* __restrict__ beta, float* __restrict__ fa,
                        float* __restrict__ fc) {
  int d = blockIdx.x * blockDim.x + threadIdx.x;
  if (d >= HS) return;
  float a = 0.f, c = 0.f;
  if (d < D_FEAT) {
    const float inv = 1.f / (float)N_NODES;
    float mu = sums[d] * inv;
    float var = sums[304 + d] * inv - mu * mu;
    a = rsqrtf(var + 1e-5f) * gamma[d];
    c = beta[d] - mu * a;
  }
  fa[d] = a;
  fc[d] = c;
}

// ---------------- BN normalize (+opt relu), 8-wide, in place on bf16 (stride HS) ----------------
__global__ void k_bnnorm(u16* __restrict__ h, const float* __restrict__ fa,
                         const float* __restrict__ fc, int relu) {
  int i = blockIdx.x * blockDim.x + threadIdx.x;  // N*38 groups of 8
  if (i >= N_NODES * 38) return;
  int n = i / 38, q = i - n * 38;
  int col = q * 8;
  u16* hp = h + (size_t)n * HS + col;
  float4 a0 = *(const float4*)(fa + col);
  float4 a1 = *(const float4*)(fa + col + 4);
  float4 c0 = *(const float4*)(fc + col);
  float4 c1 = *(const float4*)(fc + col + 4);
  ushort4 u0 = *(ushort4*)hp;
  ushort4 u1 = *(ushort4*)(hp + 4);
  float r0, r1, r2, r3, r4, r5, r6, r7;
#define BN1(res, uv, A, C)                       \
  res = fmaf((A), bf2f(uv), (C));                \
  if (relu) res = fmaxf(res, 0.f);
  BN1(r0, u0.x, a0.x, c0.x) BN1(r1, u0.y, a0.y, c0.y)
  BN1(r2, u0.z, a0.z, c0.z) BN1(r3, u0.w, a0.w, c0.w)
  BN1(r4, u1.x, a1.x, c1.x) BN1(r5, u1.y, a1.y, c1.y)
  BN1(r6, u1.z, a1.z, c1.z) BN1(r7, u1.w, a1.w, c1.w)
#undef BN1
  ushort4 o0, o1;
  o0.x = f2bf(r0); o0.y = f2bf(r1); o0.z = f2bf(r2); o0.w = f2bf(r3);
  o1.x = f2bf(r4); o1.y = f2bf(r5); o1.z = f2bf(r6); o1.w = f2bf(r7);
  *(ushort4*)hp = o0;
  *(ushort4*)(hp + 4) = o1;
}

// ---------------- segment means (sorted ids, binary search) ----------------
__device__ __forceinline__ int lowerBound(const int* __restrict__ a, int n, int v) {
  int lo = 0, hi = n;
  while (lo < hi) {
    int m = (lo + hi) >> 1;
    if (a[m] < v) lo = m + 1; else hi = m;
  }
  return lo;
}

__global__ void k_lower(const u16* __restrict__ h, const int* __restrict__ lb,
                        float* __restrict__ lower) {
  int g = blockIdx.x;
  int s = lowerBound(lb, N_NODES, g);
  int e = lowerBound(lb, N_NODES, g + 1);
  float invc = 1.f / (float)max(e - s, 1);
  for (int d = threadIdx.x; d < D_FEAT; d += 256) {
    float acc = 0.f;
    for (int r = s; r < e; r++) acc += bf2f(h[(size_t)r * HS + d]);
    lower[(size_t)g * D_FEAT + d] = acc * invc;
  }
}

__global__ void k_pooled(const float* __restrict__ lower, const int* __restrict__ ub,
                         float* __restrict__ pooled) {
  int g = blockIdx.x, br = blockIdx.y;
  int s = lowerBound(ub, L_SEG, g);
  int e = lowerBound(ub, L_SEG, g + 1);
  float invc = 1.f / (float)max(e - s, 1);
  for (int d = threadIdx.x; d < D_FEAT; d += 256) {
    float acc = 0.f;
    for (int i = s; i < e; i++) {
      int row = br ? (i - 1 + L_SEG) % L_SEG : i;
      acc += lower[(size_t)row * D_FEAT + d];
    }
    pooled[((size_t)br * G_SEG + g) * D_FEAT + d] = acc * invc;
  }
}

__global__ __launch_bounds__(256) void k_classify(const float* __restrict__ pooled,
                                                  const float* __restrict__ w1,
                                                  const float* __restrict__ b1,
                                                  const float* __restrict__ w2,
                                                  const float* __restrict__ b2,
                                                  float* __restrict__ out) {
  __shared__ float p[D_FEAT];
  __shared__ float red[4];
  int g = blockIdx.x, br = blockIdx.y;
  const float* pr = pooled + ((size_t)br * G_SEG + g) * D_FEAT;
  for (int d = threadIdx.x; d < D_FEAT; d += 256) p[d] = pr[d];
  __syncthreads();
  float partial = 0.f;
  for (int j = threadIdx.x; j < D_FEAT; j += 256) {
    float acc = b1[j];
    for (int k = 0; k < D_FEAT; k++) acc = fmaf(p[k], w1[(size_t)k * D_FEAT + j], acc);
    acc = fmaxf(acc, 0.f);
    partial += acc * w2[j];
  }
  for (int off = 32; off; off >>= 1) partial += __shfl_down(partial, off, 64);
  int lane = threadIdx.x & 63, wid = threadIdx.x >> 6;
  if (lane == 0) red[wid] = partial;
  __syncthreads();
  if (threadIdx.x == 0) out[(size_t)br * G_SEG + g] = red[0] + red[1] + red[2] + red[3] + b2[0];
}

extern "C" void kernel_launch(void* const* d_in, const int* in_sizes, int n_in,
                              void* d_out, int out_size, void* d_ws, size_t ws_size,
                              hipStream_t stream) {
  const int* x = (const int*)d_in[0];
  const int* ei = (const int*)d_in[1];
  const int* ea = (const int*)d_in[2];
  const int* lb = (const int*)d_in[3];
  const int* ub = (const int*)d_in[4];
  const float* xe1 = (const float*)d_in[5];
  const float* xe2 = (const float*)d_in[6];
  const float* ee1 = (const float*)d_in[7];
  const float* ee2 = (const float*)d_in[8];
  const float* w1 = (const float*)d_in[9];
  const float* b1 = (const float*)d_in[10];
  const float* w2 = (const float*)d_in[11];
  const float* b2 = (const float*)d_in[12];
  const float* gam = (const float*)d_in[13];
  const float* bet = (const float*)d_in[14];
  const float* cw1 = (const float*)d_in[15];
  const float* cb1 = (const float*)d_in[16];
  const float* cw2 = (const float*)d_in[17];
  const float* cb2 = (const float*)d_in[18];
  float* out = (float*)d_out;

  // ---- workspace (~172 MB; known-safe >= 255.59 MB) ----
  char* base = (char*)d_ws;
  size_t off = 0;
  auto alloc = [&](size_t bytes) -> void* {
    void* p = base + off;
    off += (bytes + 255) & ~(size_t)255;
    return p;
  };
  u16* h = (u16*)alloc((size_t)N_NODES * HS * 2);            // 79.7 MB
  u16* agg = (u16*)alloc((size_t)N_NODES * KP1 * 2);         // 83.9 MB
  u16* W1P = (u16*)alloc((size_t)NUM_LAYERS * NB1 * NK1 * 512 * 2);  // 2.05 MB
  u16* W2P = (u16*)alloc((size_t)NUM_LAYERS * NB2 * NK2 * 512 * 2);  // 2.33 MB
  int* cnt = (int*)alloc((size_t)N_NODES * 4);
  int* offs = (int*)alloc((size_t)(N_NODES + 1) * 4);
  int* cursor = (int*)alloc((size_t)N_NODES * 4);
  int* elist = (int*)alloc((size_t)E_EDGES * 4);
  float* stats = (float*)alloc(608 * 4);   // sum[0..303], sumsq[304..607]
  float* aff_a = (float*)alloc(HS * 4);
  float* aff_c = (float*)alloc(HS * 4);
  float* lower = (float*)agg;                                // alias (post-loop only)
  float* pooled = lower + (size_t)L_SEG * D_FEAT;

  if (ws_size < off) {
    k_zero<<<(out_size + 255) / 256, 256, 0, stream>>>(out, out_size);
    return;
  }

  const int NT = 256;

  k_packw<<<dim3((NB1 * NK1 * 512 + NT - 1) / NT, NUM_LAYERS), NT, 0, stream>>>(
      w1, W1P, 300, 600, NB1, NK1);
  k_packw<<<dim3((NB2 * NK2 * 512 + NT - 1) / NT, NUM_LAYERS), NT, 0, stream>>>(
      w2, W2P, 600, 300, NB2, NK2);

  k_zero<<<(N_NODES + NT - 1) / NT, NT, 0, stream>>>((float*)cnt, N_NODES);
  k_hist<<<(E_EDGES + NT - 1) / NT, NT, 0, stream>>>(ei, cnt);
  k_scan<<<1, 1024, 0, stream>>>(cnt, offs, cursor);
  k_fill<<<(E_EDGES + NT - 1) / NT, NT, 0, stream>>>(ei, cursor, elist);

  k_init_h<<<(N_NODES * 76 + NT - 1) / NT, NT, 0, stream>>>(x, xe1, xe2, h);

  for (int l = 0; l < NUM_LAYERS; l++) {
    k_gather<<<N_NODES / 4, NT, 0, stream>>>(
        (const u32*)h, ei, ea, offs, elist,
        ee1 + ((size_t)l * 6 + 4) * D_FEAT, ee2 + (size_t)l * 3 * D_FEAT,
        ee1 + (size_t)l * 6 * D_FEAT, ee2 + (size_t)l * 3 * D_FEAT, (u32*)agg);
    k_zero<<<3, NT, 0, stream>>>(stats, 608);
    k_mlp<<<N_NODES / 64, 512, 0, stream>>>(
        agg, W1P + (size_t)l * NB1 * NK1 * 512, b1 + (size_t)l * 600,
        W2P + (size_t)l * NB2 * NK2 * 512, b2 + (size_t)l * 300, h, stats);
    k_bnfin<<<2, NT, 0, stream>>>(stats, gam + (size_t)l * 300, bet + (size_t)l * 300,
                                  aff_a, aff_c);
    k_bnnorm<<<(N_NODES * 38 + NT - 1) / NT, NT, 0, stream>>>(
        h, aff_a, aff_c, l < NUM_LAYERS - 1 ? 1 : 0);
  }

  k_lower<<<L_SEG, NT, 0, stream>>>(h, lb, lower);
  dim3 gp(G_SEG, 2);
  k_pooled<<<gp, NT, 0, stream>>>(lower, ub, pooled);
  k_classify<<<gp, NT, 0, stream>>>(pooled, cw1, cb1, cw2, cb2, out);
}

// Round 20
// 1985.595 us; speedup vs baseline: 1.3420x; 1.1306x over previous
//
#include <hip/hip_runtime.h>

#define N_NODES 131072
#define E_EDGES 262144
#define L_SEG 16384
#define G_SEG 2048
#define D_FEAT 300
#define NUM_LAYERS 5
#define HS 304              // h row stride in u16 (300 data + 4 zero pad; 608B rows)
#define KP1 320             // padded K for phase 1 (agg width)
#define KP2 608             // padded K for phase 2 (T width); 19 k-steps of 32
#define NB1 40              // W1 col frag-blocks (640 cols)
#define NK1 10              // W1 k-steps (320/32)
#define NB2 24              // W2 col frag-blocks (384 cols)
#define NK2 19              // W2 k-steps (608/32)

typedef unsigned short u16;
typedef unsigned int u32;
typedef __attribute__((ext_vector_type(8))) short short8v;   // 8 bf16 = 4 VGPR
typedef __attribute__((ext_vector_type(4))) float f32x4;

struct __align__(16) U128 { u32 a, b, c, d; };   // 16B = 8 u16
struct __align__(8) U64 { u32 a, b; };           // 8B = 4 u16

// ---- bf16 <-> f32 helpers (RNE) ----
__device__ __forceinline__ float bf2f(u16 u) { return __uint_as_float(((u32)u) << 16); }
__device__ __forceinline__ u16 f2bf(float f) {
  u32 x = __float_as_uint(f);
  x += 0x7fffu + ((x >> 16) & 1u);
  return (u16)(x >> 16);
}
__device__ __forceinline__ u32 pack2(float x, float y) {
  return (u32)f2bf(x) | ((u32)f2bf(y) << 16);
}

// ---------------- h = x_emb1[x[:,0]] + x_emb2[x[:,1]]  (bf16, stride HS) ----------------
__global__ void k_init_h(const int* __restrict__ x, const float* __restrict__ e1,
                         const float* __restrict__ e2, u16* __restrict__ h) {
  int i = blockIdx.x * blockDim.x + threadIdx.x;  // N*76 ushort4 groups
  if (i >= N_NODES * 76) return;
  int n = i / 76, q = i - n * 76;
  int col = q * 4;
  ushort4 o = make_ushort4(0, 0, 0, 0);
  if (col < 300) {
    int x0 = x[2 * n], x1 = x[2 * n + 1];
    float4 va = *(const float4*)(e1 + (size_t)x0 * D_FEAT + col);
    float4 vb = *(const float4*)(e2 + (size_t)x1 * D_FEAT + col);
    o.x = f2bf(va.x + vb.x); o.y = f2bf(va.y + vb.y);
    o.z = f2bf(va.z + vb.z); o.w = f2bf(va.w + vb.w);
  }
  *(ushort4*)(h + (size_t)n * HS + col) = o;
}

// ---------------- weight pack: fragment-ordered bf16 frags ----------------
// wp block (nb, ks) = 512 u16: slot l (0..63) x 8: n = nb*16+(l&15), k = ks*32+(l>>4)*8+c.
__global__ void k_packw(const float* __restrict__ w, u16* __restrict__ wp,
                        int K, int Ncol, int NB, int NK) {
  int l = blockIdx.y;
  int i = blockIdx.x * blockDim.x + threadIdx.x;
  int tot = NB * NK * 512;
  if (i >= tot) return;
  int nb = i / (NK * 512);
  int r = i - nb * (NK * 512);
  int ks = r / 512;
  int s = r - ks * 512;
  int lane2 = s >> 3, c = s & 7;
  int n = nb * 16 + (lane2 & 15);
  int k = ks * 32 + (lane2 >> 4) * 8 + c;
  float v = (n < Ncol && k < K) ? w[(size_t)l * K * Ncol + (size_t)k * Ncol + n] : 0.f;
  wp[(size_t)l * tot + i] = f2bf(v);
}

// ---------------- CSR build ----------------
__global__ void k_zero(float* __restrict__ p, int n) {
  int i = blockIdx.x * blockDim.x + threadIdx.x;
  if (i < n) p[i] = 0.f;
}
__global__ void k_hist(const int* __restrict__ ei, int* __restrict__ cnt) {
  int e = blockIdx.x * blockDim.x + threadIdx.x;
  if (e < E_EDGES) atomicAdd(&cnt[ei[E_EDGES + e]], 1);
}
__global__ __launch_bounds__(1024) void k_scan(const int* __restrict__ cnt,
                                               int* __restrict__ offs,
                                               int* __restrict__ cursor) {
  __shared__ int part[1024];
  int t = threadIdx.x;
  int base = t * 128;
  int s = 0;
  for (int i = 0; i < 128; i++) s += cnt[base + i];
  part[t] = s;
  __syncthreads();
  for (int off = 1; off < 1024; off <<= 1) {
    int v = (t >= off) ? part[t - off] : 0;
    __syncthreads();
    part[t] += v;
    __syncthreads();
  }
  int run = (t == 0) ? 0 : part[t - 1];
  for (int i = 0; i < 128; i++) {
    offs[base + i] = run;
    cursor[base + i] = run;
    run += cnt[base + i];
  }
  if (t == 1023) offs[N_NODES] = run;
}
__global__ void k_fill(const int* __restrict__ ei, int* __restrict__ cursor,
                       int* __restrict__ elist) {
  int e = blockIdx.x * blockDim.x + threadIdx.x;
  if (e < E_EDGES) {
    int p = atomicAdd(&cursor[ei[E_EDGES + e]], 1);
    elist[p] = e;
  }
}

// ---------------- gather-aggregate (h already normalized) ----------------
__global__ void k_gather(const u32* __restrict__ h, const int* __restrict__ ei,
                         const int* __restrict__ ea, const int* __restrict__ offs,
                         const int* __restrict__ elist, const float* __restrict__ sc1,
                         const float* __restrict__ sc2, const float* __restrict__ ee1,
                         const float* __restrict__ ee2, u32* __restrict__ agg) {
  int n = (blockIdx.x << 2) + (threadIdx.x >> 6);
  int lane = threadIdx.x & 63;
  int j0 = lane, j1 = lane + 64, j2 = lane + 128;  // u32 indices (data < 150)
  float ax0, ay0, ax1, ay1, ax2 = 0.f, ay2 = 0.f;
  const u32* hn = h + (size_t)n * (HS / 2);
  {
    u32 u = hn[j0];
    ax0 = bf2f((u16)(u & 0xffffu)) + sc1[2 * j0] + sc2[2 * j0];
    ay0 = bf2f((u16)(u >> 16)) + sc1[2 * j0 + 1] + sc2[2 * j0 + 1];
    u = hn[j1];
    ax1 = bf2f((u16)(u & 0xffffu)) + sc1[2 * j1] + sc2[2 * j1];
    ay1 = bf2f((u16)(u >> 16)) + sc1[2 * j1 + 1] + sc2[2 * j1 + 1];
    if (j2 < 150) {
      u = hn[j2];
      ax2 = bf2f((u16)(u & 0xffffu)) + sc1[2 * j2] + sc2[2 * j2];
      ay2 = bf2f((u16)(u >> 16)) + sc1[2 * j2 + 1] + sc2[2 * j2 + 1];
    }
  }
  int p = offs[n], pe = offs[n + 1];
  while (p + 2 <= pe) {
    int eA = elist[p], eB = elist[p + 1];
    int sA = ei[eA], sB = ei[eB];
    int a0A = ea[2 * eA], a1A = ea[2 * eA + 1];
    int a0B = ea[2 * eB], a1B = ea[2 * eB + 1];
    const u32* hA = h + (size_t)sA * (HS / 2);
    const u32* hB = h + (size_t)sB * (HS / 2);
    const float* p1A = ee1 + (size_t)a0A * D_FEAT;
    const float* p2A = ee2 + (size_t)a1A * D_FEAT;
    const float* p1B = ee1 + (size_t)a0B * D_FEAT;
    const float* p2B = ee2 + (size_t)a1B * D_FEAT;
    u32 uA0 = hA[j0], uA1 = hA[j1];
    u32 uB0 = hB[j0], uB1 = hB[j1];
    u32 uA2 = 0, uB2 = 0;
    if (j2 < 150) { uA2 = hA[j2]; uB2 = hB[j2]; }
    ax0 += bf2f((u16)(uA0 & 0xffffu)) + p1A[2 * j0] + p2A[2 * j0];
    ay0 += bf2f((u16)(uA0 >> 16)) + p1A[2 * j0 + 1] + p2A[2 * j0 + 1];
    ax1 += bf2f((u16)(uA1 & 0xffffu)) + p1A[2 * j1] + p2A[2 * j1];
    ay1 += bf2f((u16)(uA1 >> 16)) + p1A[2 * j1 + 1] + p2A[2 * j1 + 1];
    if (j2 < 150) {
      ax2 += bf2f((u16)(uA2 & 0xffffu)) + p1A[2 * j2] + p2A[2 * j2];
      ay2 += bf2f((u16)(uA2 >> 16)) + p1A[2 * j2 + 1] + p2A[2 * j2 + 1];
    }
    ax0 += bf2f((u16)(uB0 & 0xffffu)) + p1B[2 * j0] + p2B[2 * j0];
    ay0 += bf2f((u16)(uB0 >> 16)) + p1B[2 * j0 + 1] + p2B[2 * j0 + 1];
    ax1 += bf2f((u16)(uB1 & 0xffffu)) + p1B[2 * j1] + p2B[2 * j1];
    ay1 += bf2f((u16)(uB1 >> 16)) + p1B[2 * j1 + 1] + p2B[2 * j1 + 1];
    if (j2 < 150) {
      ax2 += bf2f((u16)(uB2 & 0xffffu)) + p1B[2 * j2] + p2B[2 * j2];
      ay2 += bf2f((u16)(uB2 >> 16)) + p1B[2 * j2 + 1] + p2B[2 * j2 + 1];
    }
    p += 2;
  }
  if (p < pe) {  // tail edge
    int e = elist[p];
    int s = ei[e];
    int a0 = ea[2 * e], a1 = ea[2 * e + 1];
    const u32* hs = h + (size_t)s * (HS / 2);
    const float* p1 = ee1 + (size_t)a0 * D_FEAT;
    const float* p2 = ee2 + (size_t)a1 * D_FEAT;
    u32 u = hs[j0];
    ax0 += bf2f((u16)(u & 0xffffu)) + p1[2 * j0] + p2[2 * j0];
    ay0 += bf2f((u16)(u >> 16)) + p1[2 * j0 + 1] + p2[2 * j0 + 1];
    u = hs[j1];
    ax1 += bf2f((u16)(u & 0xffffu)) + p1[2 * j1] + p2[2 * j1];
    ay1 += bf2f((u16)(u >> 16)) + p1[2 * j1 + 1] + p2[2 * j1 + 1];
    if (j2 < 150) {
      u = hs[j2];
      ax2 += bf2f((u16)(u & 0xffffu)) + p1[2 * j2] + p2[2 * j2];
      ay2 += bf2f((u16)(u >> 16)) + p1[2 * j2 + 1] + p2[2 * j2 + 1];
    }
  }
  u32* ao = agg + (size_t)n * (KP1 / 2);
  ao[j0] = pack2(ax0, ay0);
  ao[j1] = pack2(ax1, ay1);
  if (j2 < 150) ao[j2] = pack2(ax2, ay2);
  else if (j2 < 160) ao[j2] = 0u;
}

// ---------------- FUSED MLP: h = relu(agg@W1+b1)@W2+b2 (one dispatch/layer) --------------
// R19 structure, re-blocked for occupancy: 32 rows/block (512 thr, 8 waves), each
// wave owns a COLUMN slice (phase 1: 5 frags = 80 cols; phase 2: 3 frags = 48 cols).
// TL = 2 rowblocks x NK2 x 512 u16 = 38 KB -> 4 blocks/CU (was 76 KB -> 2).
// Slot algebra identical to R19, computed directly from col:
//   T elem (row, col) -> block (row/16, col>>5), u16 = (((col>>3)&3)*16 + row%16)*8 + (col&7)
__global__ __launch_bounds__(512) void k_mlp(const u16* __restrict__ agg,
                                             const u16* __restrict__ W1P,
                                             const float* __restrict__ b1,
                                             const u16* __restrict__ W2P,
                                             const float* __restrict__ b2,
                                             u16* __restrict__ h,
                                             float* __restrict__ stats) {
  __shared__ __align__(16) u16 TL[2 * NK2 * 512];  // 19456 u16 = 38 KB; HT (32x392) aliases
  int t = threadIdx.x;
  int w = t >> 6, lane = t & 63;
  int r16 = lane & 15, kq = lane >> 4, rq = kq << 2;
  int brow = blockIdx.x << 5;  // 32 rows/block

  f32x4 zero4 = {0.f, 0.f, 0.f, 0.f};

  // ---- phase 1: 32x640, K=320; wave w owns cols w*80 .. w*80+79 ----
  f32x4 acc1[2][5];
#pragma unroll
  for (int fr = 0; fr < 2; fr++)
#pragma unroll
    for (int fc = 0; fc < 5; fc++) acc1[fr][fc] = zero4;

  const u16* Ab = agg + (size_t)(brow + r16) * KP1 + kq * 8;
  const u16* W1w = W1P + (size_t)(w * 5) * NK1 * 512 + lane * 8;
  for (int ks = 0; ks < NK1; ks++) {
    short8v af0 = *(const short8v*)(Ab + ks * 32);
    short8v af1 = *(const short8v*)(Ab + 16 * KP1 + ks * 32);
#pragma unroll
    for (int fc = 0; fc < 5; fc++) {
      short8v bf = *(const short8v*)(W1w + (size_t)(fc * NK1 + ks) * 512);
      acc1[0][fc] = __builtin_amdgcn_mfma_f32_16x16x32_bf16(af0, bf, acc1[0][fc], 0, 0, 0);
      acc1[1][fc] = __builtin_amdgcn_mfma_f32_16x16x32_bf16(af1, bf, acc1[1][fc], 0, 0, 0);
    }
  }

  // write T = relu(acc1 + b1) into TL, phase-2 fragment order
#pragma unroll
  for (int fc = 0; fc < 5; fc++) {
    int col = w * 80 + fc * 16 + r16;
    if (col < KP2) {  // cols 608..639 dropped (zero contribution; W2P k-pad is zero)
      float bs = (col < 600) ? b1[col] : 0.f;
      int ks2 = col >> 5;
      int coff = ((col >> 3) & 3) * 128 + (r16 & 7);
#pragma unroll
      for (int fr = 0; fr < 2; fr++) {
        u16* blk = TL + (size_t)(fr * NK2 + ks2) * 512;
#pragma unroll
        for (int j = 0; j < 4; j++) {
          float v = fmaxf(acc1[fr][fc][j] + bs, 0.f);
          blk[coff + (rq + j) * 8] = f2bf(v);
        }
      }
    }
  }
  __syncthreads();  // T complete

  // ---- phase 2: 32x384, K=608; wave w owns cols w*48 .. w*48+47 ----
  f32x4 acc2[2][3];
#pragma unroll
  for (int fr = 0; fr < 2; fr++)
#pragma unroll
    for (int fc = 0; fc < 3; fc++) acc2[fr][fc] = zero4;

  const u16* W2w = W2P + (size_t)(w * 3) * NK2 * 512 + lane * 8;
  for (int ks = 0; ks < NK2; ks++) {
    short8v af0 = *(const short8v*)(TL + (size_t)(0 * NK2 + ks) * 512 + lane * 8);
    short8v af1 = *(const short8v*)(TL + (size_t)(1 * NK2 + ks) * 512 + lane * 8);
#pragma unroll
    for (int fc = 0; fc < 3; fc++) {
      short8v bf = *(const short8v*)(W2w + (size_t)(fc * NK2 + ks) * 512);
      acc2[0][fc] = __builtin_amdgcn_mfma_f32_16x16x32_bf16(af0, bf, acc2[0][fc], 0, 0, 0);
      acc2[1][fc] = __builtin_amdgcn_mfma_f32_16x16x32_bf16(af1, bf, acc2[1][fc], 0, 0, 0);
    }
  }
  __syncthreads();  // all TL reads done; reuse as HT[32][392]

  u16* HT = TL;
#pragma unroll
  for (int fc = 0; fc < 3; fc++) {
    int col = w * 48 + fc * 16 + r16;
    bool live = col < 300;
    float bs = live ? b2[col] : 0.f;
#pragma unroll
    for (int fr = 0; fr < 2; fr++) {
      int row = fr * 16 + rq;
#pragma unroll
      for (int j = 0; j < 4; j++) {
        float v = acc2[fr][fc][j] + bs;
        if (!live) v = 0.f;
        HT[(size_t)(row + j) * 392 + col] = f2bf(v);
      }
    }
  }
  __syncthreads();

  // coalesced h store: 32 rows x 304 u16 = 38 U128 chunks/row
  for (int i = t; i < 32 * 38; i += 512) {
    int r = i / 38, c8 = (i - r * 38) * 8;
    U128 v = *(const U128*)(HT + (size_t)r * 392 + c8);
    *(U128*)(h + (size_t)(brow + r) * HS + c8) = v;
  }
  // fused column stats over the 32 rows (bf16 bits == what h stores)
  if (t < 300) {
    float s0 = 0.f, q0 = 0.f;
#pragma unroll 8
    for (int r = 0; r < 32; r++) {
      float v = bf2f(HT[(size_t)r * 392 + t]);
      s0 += v;
      q0 = fmaf(v, v, q0);
    }
    atomicAdd(stats + t, s0);
    atomicAdd(stats + 304 + t, q0);
  }
}

// ---------------- BN finalize: a = rsqrt(var+eps)*gamma, c = beta - mu*a (pads -> 0) ----------------
__global__ void k_bnfin(const float* __restrict__ sums, const float* __restrict__ gamma,
                        const float* __restrict__ beta, float* __restrict__ fa,
                        float* __restrict__ fc) {
  int d = blockIdx.x * blockDim.x + threadIdx.x;
  if (d >= HS) return;
  float a = 0.f, c = 0.f;
  if (d < D_FEAT) {
    const float inv = 1.f / (float)N_NODES;
    float mu = sums[d] * inv;
    float var = sums[304 + d] * inv - mu * mu;
    a = rsqrtf(var + 1e-5f) * gamma[d];
    c = beta[d] - mu * a;
  }
  fa[d] = a;
  fc[d] = c;
}

// ---------------- BN normalize (+opt relu), 8-wide, in place on bf16 (stride HS) ----------------
__global__ void k_bnnorm(u16* __restrict__ h, const float* __restrict__ fa,
                         const float* __restrict__ fc, int relu) {
  int i = blockIdx.x * blockDim.x + threadIdx.x;  // N*38 groups of 8
  if (i >= N_NODES * 38) return;
  int n = i / 38, q = i - n * 38;
  int col = q * 8;
  u16* hp = h + (size_t)n * HS + col;
  float4 a0 = *(const float4*)(fa + col);
  float4 a1 = *(const float4*)(fa + col + 4);
  float4 c0 = *(const float4*)(fc + col);
  float4 c1 = *(const float4*)(fc + col + 4);
  ushort4 u0 = *(ushort4*)hp;
  ushort4 u1 = *(ushort4*)(hp + 4);
  float r0, r1, r2, r3, r4, r5, r6, r7;
#define BN1(res, uv, A, C)                       \
  res = fmaf((A), bf2f(uv), (C));                \
  if (relu) res = fmaxf(res, 0.f);
  BN1(r0, u0.x, a0.x, c0.x) BN1(r1, u0.y, a0.y, c0.y)
  BN1(r2, u0.z, a0.z, c0.z) BN1(r3, u0.w, a0.w, c0.w)
  BN1(r4, u1.x, a1.x, c1.x) BN1(r5, u1.y, a1.y, c1.y)
  BN1(r6, u1.z, a1.z, c1.z) BN1(r7, u1.w, a1.w, c1.w)
#undef BN1
  ushort4 o0, o1;
  o0.x = f2bf(r0); o0.y = f2bf(r1); o0.z = f2bf(r2); o0.w = f2bf(r3);
  o1.x = f2bf(r4); o1.y = f2bf(r5); o1.z = f2bf(r6); o1.w = f2bf(r7);
  *(ushort4*)hp = o0;
  *(ushort4*)(hp + 4) = o1;
}

// ---------------- segment means (sorted ids, binary search) ----------------
__device__ __forceinline__ int lowerBound(const int* __restrict__ a, int n, int v) {
  int lo = 0, hi = n;
  while (lo < hi) {
    int m = (lo + hi) >> 1;
    if (a[m] < v) lo = m + 1; else hi = m;
  }
  return lo;
}

__global__ void k_lower(const u16* __restrict__ h, const int* __restrict__ lb,
                        float* __restrict__ lower) {
  int g = blockIdx.x;
  int s = lowerBound(lb, N_NODES, g);
  int e = lowerBound(lb, N_NODES, g + 1);
  float invc = 1.f / (float)max(e - s, 1);
  for (int d = threadIdx.x; d < D_FEAT; d += 256) {
    float acc = 0.f;
    for (int r = s; r < e; r++) acc += bf2f(h[(size_t)r * HS + d]);
    lower[(size_t)g * D_FEAT + d] = acc * invc;
  }
}

__global__ void k_pooled(const float* __restrict__ lower, const int* __restrict__ ub,
                         float* __restrict__ pooled) {
  int g = blockIdx.x, br = blockIdx.y;
  int s = lowerBound(ub, L_SEG, g);
  int e = lowerBound(ub, L_SEG, g + 1);
  float invc = 1.f / (float)max(e - s, 1);
  for (int d = threadIdx.x; d < D_FEAT; d += 256) {
    float acc = 0.f;
    for (int i = s; i < e; i++) {
      int row = br ? (i - 1 + L_SEG) % L_SEG : i;
      acc += lower[(size_t)row * D_FEAT + d];
    }
    pooled[((size_t)br * G_SEG + g) * D_FEAT + d] = acc * invc;
  }
}

__global__ __launch_bounds__(256) void k_classify(const float* __restrict__ pooled,
                                                  const float* __restrict__ w1,
                                                  const float* __restrict__ b1,
                                                  const float* __restrict__ w2,
                                                  const float* __restrict__ b2,
                                                  float* __restrict__ out) {
  __shared__ float p[D_FEAT];
  __shared__ float red[4];
  int g = blockIdx.x, br = blockIdx.y;
  const float* pr = pooled + ((size_t)br * G_SEG + g) * D_FEAT;
  for (int d = threadIdx.x; d < D_FEAT; d += 256) p[d] = pr[d];
  __syncthreads();
  float partial = 0.f;
  for (int j = threadIdx.x; j < D_FEAT; j += 256) {
    float acc = b1[j];
    for (int k = 0; k < D_FEAT; k++) acc = fmaf(p[k], w1[(size_t)k * D_FEAT + j], acc);
    acc = fmaxf(acc, 0.f);
    partial += acc * w2[j];
  }
  for (int off = 32; off; off >>= 1) partial += __shfl_down(partial, off, 64);
  int lane = threadIdx.x & 63, wid = threadIdx.x >> 6;
  if (lane == 0) red[wid] = partial;
  __syncthreads();
  if (threadIdx.x == 0) out[(size_t)br * G_SEG + g] = red[0] + red[1] + red[2] + red[3] + b2[0];
}

extern "C" void kernel_launch(void* const* d_in, const int* in_sizes, int n_in,
                              void* d_out, int out_size, void* d_ws, size_t ws_size,
                              hipStream_t stream) {
  const int* x = (const int*)d_in[0];
  const int* ei = (const int*)d_in[1];
  const int* ea = (const int*)d_in[2];
  const int* lb = (const int*)d_in[3];
  const int* ub = (const int*)d_in[4];
  const float* xe1 = (const float*)d_in[5];
  const float* xe2 = (const float*)d_in[6];
  const float* ee1 = (const float*)d_in[7];
  const float* ee2 = (const float*)d_in[8];
  const float* w1 = (const float*)d_in[9];
  const float* b1 = (const float*)d_in[10];
  const float* w2 = (const float*)d_in[11];
  const float* b2 = (const float*)d_in[12];
  const float* gam = (const float*)d_in[13];
  const float* bet = (const float*)d_in[14];
  const float* cw1 = (const float*)d_in[15];
  const float* cb1 = (const float*)d_in[16];
  const float* cw2 = (const float*)d_in[17];
  const float* cb2 = (const float*)d_in[18];
  float* out = (float*)d_out;

  // ---- workspace (~172 MB; known-safe >= 255.59 MB) ----
  char* base = (char*)d_ws;
  size_t off = 0;
  auto alloc = [&](size_t bytes) -> void* {
    void* p = base + off;
    off += (bytes + 255) & ~(size_t)255;
    return p;
  };
  u16* h = (u16*)alloc((size_t)N_NODES * HS * 2);            // 79.7 MB
  u16* agg = (u16*)alloc((size_t)N_NODES * KP1 * 2);         // 83.9 MB
  u16* W1P = (u16*)alloc((size_t)NUM_LAYERS * NB1 * NK1 * 512 * 2);  // 2.05 MB
  u16* W2P = (u16*)alloc((size_t)NUM_LAYERS * NB2 * NK2 * 512 * 2);  // 2.33 MB
  int* cnt = (int*)alloc((size_t)N_NODES * 4);
  int* offs = (int*)alloc((size_t)(N_NODES + 1) * 4);
  int* cursor = (int*)alloc((size_t)N_NODES * 4);
  int* elist = (int*)alloc((size_t)E_EDGES * 4);
  float* stats = (float*)alloc(608 * 4);   // sum[0..303], sumsq[304..607]
  float* aff_a = (float*)alloc(HS * 4);
  float* aff_c = (float*)alloc(HS * 4);
  float* lower = (float*)agg;                                // alias (post-loop only)
  float* pooled = lower + (size_t)L_SEG * D_FEAT;

  if (ws_size < off) {
    k_zero<<<(out_size + 255) / 256, 256, 0, stream>>>(out, out_size);
    return;
  }

  const int NT = 256;

  k_packw<<<dim3((NB1 * NK1 * 512 + NT - 1) / NT, NUM_LAYERS), NT, 0, stream>>>(
      w1, W1P, 300, 600, NB1, NK1);
  k_packw<<<dim3((NB2 * NK2 * 512 + NT - 1) / NT, NUM_LAYERS), NT, 0, stream>>>(
      w2, W2P, 600, 300, NB2, NK2);

  k_zero<<<(N_NODES + NT - 1) / NT, NT, 0, stream>>>((float*)cnt, N_NODES);
  k_hist<<<(E_EDGES + NT - 1) / NT, NT, 0, stream>>>(ei, cnt);
  k_scan<<<1, 1024, 0, stream>>>(cnt, offs, cursor);
  k_fill<<<(E_EDGES + NT - 1) / NT, NT, 0, stream>>>(ei, cursor, elist);

  k_init_h<<<(N_NODES * 76 + NT - 1) / NT, NT, 0, stream>>>(x, xe1, xe2, h);

  for (int l = 0; l < NUM_LAYERS; l++) {
    k_gather<<<N_NODES / 4, NT, 0, stream>>>(
        (const u32*)h, ei, ea, offs, elist,
        ee1 + ((size_t)l * 6 + 4) * D_FEAT, ee2 + (size_t)l * 3 * D_FEAT,
        ee1 + (size_t)l * 6 * D_FEAT, ee2 + (size_t)l * 3 * D_FEAT, (u32*)agg);
    k_zero<<<3, NT, 0, stream>>>(stats, 608);
    k_mlp<<<N_NODES / 32, 512, 0, stream>>>(
        agg, W1P + (size_t)l * NB1 * NK1 * 512, b1 + (size_t)l * 600,
        W2P + (size_t)l * NB2 * NK2 * 512, b2 + (size_t)l * 300, h, stats);
    k_bnfin<<<2, NT, 0, stream>>>(stats, gam + (size_t)l * 300, bet + (size_t)l * 300,
                                  aff_a, aff_c);
    k_bnnorm<<<(N_NODES * 38 + NT - 1) / NT, NT, 0, stream>>>(
        h, aff_a, aff_c, l < NUM_LAYERS - 1 ? 1 : 0);
  }

  k_lower<<<L_SEG, NT, 0, stream>>>(h, lb, lower);
  dim3 gp(G_SEG, 2);
  k_pooled<<<gp, NT, 0, stream>>>(lower, ub, pooled);
  k_classify<<<gp, NT, 0, stream>>>(pooled, cw1, cb1, cw2, cb2, out);
}